// Round 14
// baseline (405.170 us; speedup 1.0000x reference)
//
#include <hip/hip_runtime.h>
#include <stdint.h>

#define NTOK 8192
#define DDIM 1024
#define NEXP 16
#define KSEL 2
#define ISH 2048
#define IEX 512
#define ALPHAC 1e-4f
#define REPS 1e-9f

typedef __attribute__((ext_vector_type(4))) float f32x4;

__device__ __forceinline__ unsigned short f2bf(float f){
  union { float f; uint32_t u; } v; v.f = f;
  uint32_t u = v.u;
  uint32_t r = (u + 0x7fffu + ((u >> 16) & 1u)) >> 16;
  return (unsigned short)r;
}
__device__ __forceinline__ float bf2f(unsigned short h){
  union { uint32_t u; float f; } v; v.u = ((uint32_t)h) << 16; return v.f;
}

// f32 -> OCP e4m3fn, RNE, saturating to +-448. Software encoder (no asm/header dep).
__device__ __forceinline__ unsigned char f2fp8(float x){
  union{ float f; uint32_t u; } v; v.f = x;
  unsigned char sgn = (unsigned char)((v.u >> 31) << 7);
  uint32_t au = v.u & 0x7fffffffu;
  if (au >= 0x43E80000u) return sgn | 0x7E;     // |x| >= 464 -> 448 (0x7F is NaN)
  if (au <  0x3A800000u) return sgn;            // |x| < 2^-10 -> 0
  int e  = (int)(au >> 23) - 127;               // floor(log2|x|)
  int ee = e < -6 ? -6 : e;
  float scale = __uint_as_float((uint32_t)(127 + 3 - ee) << 23);  // 2^(3-ee)
  int qi = (int)rintf(__uint_as_float(au) * scale);               // ulp count, RNE
  int exp8, man;
  if (qi >= 16)     { exp8 = ee + 8; man = 0; }        // rounded to next binade
  else if (qi >= 8) { exp8 = ee + 7; man = qi - 8; }   // normal
  else              { exp8 = 0;      man = qi; }       // subnormal (ee = -6)
  return sgn | (unsigned char)((exp8 << 3) | man);
}

// async global->LDS, 16B per lane; LDS dest = wave-uniform base + lane*16
__device__ __forceinline__ void gload16(const void* g, void* l){
  __builtin_amdgcn_global_load_lds(
      (const __attribute__((address_space(1))) void*)g,
      (__attribute__((address_space(3))) void*)l, 16, 0, 0);
}

// ------- transpose + convert: in (R,C) f32 -> out row (c*RM+RO) of length R, fp8 -------
template<int RM, int RO>
__global__ __launch_bounds__(256) void transpose_fp8(const float* __restrict__ in,
                                                     unsigned char* __restrict__ outp,
                                                     int R, int C){
  __shared__ float tile[64][65];
  const float* ip = in + (size_t)blockIdx.z * R * C;
  unsigned char* op = outp + (size_t)blockIdx.z * R * C * RM;
  int c0 = blockIdx.x * 64, r0 = blockIdx.y * 64;
  int t = threadIdx.x;
  int tr = t >> 4, tc = (t & 15) * 4;
  #pragma unroll
  for (int i = 0; i < 4; ++i){
    float4 v = *(const float4*)&ip[(size_t)(r0 + tr + i*16) * C + c0 + tc];
    tile[tr + i*16][tc+0] = v.x;
    tile[tr + i*16][tc+1] = v.y;
    tile[tr + i*16][tc+2] = v.z;
    tile[tr + i*16][tc+3] = v.w;
  }
  __syncthreads();
  #pragma unroll
  for (int i = 0; i < 4; ++i){
    int oc = tr + i*16;
    uchar4 w;
    w.x = f2fp8(tile[tc+0][oc]);
    w.y = f2fp8(tile[tc+1][oc]);
    w.z = f2fp8(tile[tc+2][oc]);
    w.w = f2fp8(tile[tc+3][oc]);
    *(uchar4*)&op[(size_t)((c0 + oc) * RM + RO) * R + r0 + tc] = w;
  }
}

// ------- router stage 1: fp32 logits = x @ gw, wave-per-token; ALSO writes xb (fp8) -------
__global__ __launch_bounds__(256) void logits_kernel(
    const float* __restrict__ x, const float* __restrict__ gw,
    float* __restrict__ logits, unsigned char* __restrict__ xb)
{
  __shared__ float gws[16][1024];
  const int t = threadIdx.x;
  #pragma unroll
  for (int k = 0; k < 16; ++k){
    int idx = t + k * 256;
    float4 v = ((const float4*)gw)[idx];
    int d = idx >> 2, e0 = (idx & 3) * 4;
    gws[e0+0][d] = v.x;
    gws[e0+1][d] = v.y;
    gws[e0+2][d] = v.z;
    gws[e0+3][d] = v.w;
  }
  __syncthreads();
  const int lane = t & 63, w = t >> 6;
  const int nb = blockIdx.x * 16 + w * 4;
  for (int i = 0; i < 4; ++i){
    const int n = nb + i;
    const float4* xr = (const float4*)(x + (size_t)n * DDIM);
    uchar4* xo = (uchar4*)(xb + (size_t)n * DDIM);
    float4 xv[4];
    #pragma unroll
    for (int k = 0; k < 4; ++k) xv[k] = xr[lane + k*64];
    #pragma unroll
    for (int k = 0; k < 4; ++k){
      uchar4 ob;
      ob.x = f2fp8(xv[k].x); ob.y = f2fp8(xv[k].y);
      ob.z = f2fp8(xv[k].z); ob.w = f2fp8(xv[k].w);
      xo[lane + k*64] = ob;                 // fused f32->fp8 convert of x
    }
    float acc[16];
    #pragma unroll
    for (int e = 0; e < 16; ++e){
      float s = 0.f;
      #pragma unroll
      for (int k = 0; k < 4; ++k){
        float4 g = *(const float4*)&gws[e][(lane + k*64)*4];
        s = fmaf(xv[k].x, g.x, fmaf(xv[k].y, g.y, fmaf(xv[k].z, g.z, fmaf(xv[k].w, g.w, s))));
      }
      acc[e] = s;
    }
    #pragma unroll
    for (int m = 1; m < 64; m <<= 1)
      #pragma unroll
      for (int e = 0; e < 16; ++e)
        acc[e] += __shfl_xor(acc[e], m);
    if (lane == 0){
      float4* op = (float4*)(logits + (size_t)n * 16);
      op[0] = make_float4(acc[0],  acc[1],  acc[2],  acc[3]);
      op[1] = make_float4(acc[4],  acc[5],  acc[6],  acc[7]);
      op[2] = make_float4(acc[8],  acc[9],  acc[10], acc[11]);
      op[3] = make_float4(acc[12], acc[13], acc[14], acc[15]);
    }
  }
}

// ---------------- router stage 2: sigmoid, top-2, gates, P/C partials ----------------
__global__ __launch_bounds__(256) void router_finish(
    const float* __restrict__ logits, const float* __restrict__ ebias,
    int* __restrict__ idxb, float* __restrict__ gvb,
    float* __restrict__ Ppart, int* __restrict__ Cpart)
{
  __shared__ float Ps[16];
  __shared__ int Cs[16];
  const int t = threadIdx.x;
  if (t < 16){ Ps[t] = 0.f; Cs[t] = 0; }
  __syncthreads();
  const int lane = t & 63;
  const int n = blockIdx.x * 256 + t;
  const float4* lp = (const float4*)(logits + (size_t)n * 16);
  float4 a0 = lp[0], a1 = lp[1], a2 = lp[2], a3 = lp[3];
  float aff[16];
  aff[0]=a0.x; aff[1]=a0.y; aff[2]=a0.z; aff[3]=a0.w;
  aff[4]=a1.x; aff[5]=a1.y; aff[6]=a1.z; aff[7]=a1.w;
  aff[8]=a2.x; aff[9]=a2.y; aff[10]=a2.z; aff[11]=a2.w;
  aff[12]=a3.x; aff[13]=a3.y; aff[14]=a3.z; aff[15]=a3.w;
  float rowsum = REPS;
  #pragma unroll
  for (int e = 0; e < 16; ++e){
    aff[e] = 1.f / (1.f + __expf(-aff[e]));
    rowsum += aff[e];
  }
  float bj[16];
  #pragma unroll
  for (int e = 0; e < 16; ++e) bj[e] = ebias[e];
  float bestS = aff[0] + bj[0], bestA = aff[0]; int i1 = 0;
  #pragma unroll
  for (int j = 1; j < 16; ++j){
    float sc = aff[j] + bj[j];
    bool gt2 = sc > bestS;
    bestS = gt2 ? sc : bestS; bestA = gt2 ? aff[j] : bestA; i1 = gt2 ? j : i1;
  }
  float secS = -1e30f, secA = 0.f; int i2 = 0;
  #pragma unroll
  for (int j = 0; j < 16; ++j){
    float sc = aff[j] + bj[j];
    bool ok = (j != i1) && (sc > secS);
    secS = ok ? sc : secS; secA = ok ? aff[j] : secA; i2 = ok ? j : i2;
  }
  float den = bestA + secA + REPS;
  idxb[n*2]   = i1; idxb[n*2+1] = i2;
  gvb[n*2]    = bestA / den; gvb[n*2+1] = secA / den;

  float inv = 1.f / rowsum;
  float pv[16]; int cv[16];
  #pragma unroll
  for (int e = 0; e < 16; ++e){
    pv[e] = aff[e] * inv;
    cv[e] = (e == i1) + (e == i2);
  }
  #pragma unroll
  for (int m = 1; m < 64; m <<= 1)
    #pragma unroll
    for (int e = 0; e < 16; ++e){
      pv[e] += __shfl_xor(pv[e], m);
      cv[e] += __shfl_xor(cv[e], m);
    }
  if (lane == 0){
    #pragma unroll
    for (int e = 0; e < 16; ++e){
      atomicAdd(&Ps[e], pv[e]);
      atomicAdd(&Cs[e], cv[e]);
    }
  }
  __syncthreads();
  if (t < 16){ Ppart[blockIdx.x*16 + t] = Ps[t]; Cpart[blockIdx.x*16 + t] = Cs[t]; }
}

// ---------------- finalize: counts, offsets, cursors, balance loss, tail writes ----------------
__global__ __launch_bounds__(256) void finalize2(
    const float* __restrict__ Ppart, const int* __restrict__ Cpart,
    int* __restrict__ counts, int* __restrict__ offs, int* __restrict__ cursor,
    float* __restrict__ out_tail)
{
  __shared__ float P[16];
  __shared__ int C[16];
  int t = threadIdx.x;
  if (t < 16){ P[t] = 0.f; C[t] = 0; }
  __syncthreads();
  if (t < 32){
    int e = t & 15, c = t >> 4;
    float p = 0.f; int cc = 0;
    for (int b = c * 16; b < c * 16 + 16; ++b){ p += Ppart[b*16 + e]; cc += Cpart[b*16 + e]; }
    atomicAdd(&P[e], p); atomicAdd(&C[e], cc);
  }
  __syncthreads();
  if (t == 0){
    int a = 0; float loss = 0.f;
    for (int i = 0; i < 16; ++i){
      offs[i] = a; cursor[i] = a; counts[i] = C[i]; a += C[i];
      loss += ((float)C[i] * (float)NEXP / (float)(KSEL * NTOK)) * (P[i] / (float)NTOK);
      out_tail[1+i] = (float)C[i];
    }
    out_tail[0] = ALPHAC * loss;
  }
}

// ---------------- slot assignment into per-expert contiguous groups ----------------
__global__ __launch_bounds__(256) void slot_assign(
    const int* __restrict__ idxb, const float* __restrict__ gvb,
    int* __restrict__ cursor, int* __restrict__ tokp, float* __restrict__ gatep,
    int* __restrict__ rslot)
{
  int i = blockIdx.x * 256 + threadIdx.x;   // (n,k) flat, 0..16383
  int e = idxb[i];
  int s = atomicAdd(&cursor[e], 1);
  tokp[s] = i >> 1;
  gatep[s] = gvb[i];
  rslot[i] = s;
}

// ---------------- 128x128xBK128 fp8 MFMA GEMM, single-buffered (m97 structure) ----------
// A: MxK row-major fp8, B: NxK row-major fp8 (= B^T). LDS 32KB single-buffer (same
// footprint as the measured bf16/BK64 config -> same occupancy) but HALF the barriers
// per K and half the staged bytes. mfma_f32_16x16x32_fp8_fp8 (bf16 rate, K=32).
// Swizzle: 16B-slot source XOR (row>>1)&7; ds_read_b64 at ((ks*4+g)^(row&14))*8 -> <=2-way.
// MODE: 1 = f32 store; 2 = bf16 * rowscale;
//       6 = interleaved gate/up -> silu(even col)*odd col, store N/2 cols fp8;
//       7 = f32 store of val + yb[perm[2*row]][col] + yb[perm[2*row+1]][col] (fused combine).
template<bool GROUPED, bool GATHER, int MODE, int NYT>
__global__ __launch_bounds__(256) void gemm128(
    const unsigned char* __restrict__ A,
    const unsigned char* __restrict__ B,
    void* __restrict__ Cout,
    int M, int N, int K,
    const int* __restrict__ counts,
    const int* __restrict__ offsets,
    const int* __restrict__ perm,
    const float* __restrict__ rowscale,
    const unsigned short* __restrict__ yb)
{
  __shared__ __align__(16) unsigned char As[128*128];
  __shared__ __align__(16) unsigned char Bs[128*128];

  const int nwg = gridDim.x;
  const int bid = blockIdx.x;
  const int wg = (bid & 7) * (nwg >> 3) + (bid >> 3);   // XCD-contiguous chunks
  const int mtl = wg / NYT;
  const int nt  = wg % NYT;

  int mt = mtl, off = 0, cnt = M;
  const unsigned char* bp = B;
  if (GROUPED){
    int acc_ = 0, e = -1;
    #pragma unroll
    for (int i = 0; i < NEXP; ++i){
      int c = counts[i]; int tt = (c + 127) >> 7;
      if (e < 0 && mtl < acc_ + tt){ e = i; mt = mtl - acc_; off = offsets[i]; cnt = c; }
      acc_ += tt;
    }
    if (e < 0) return;
    bp += (size_t)e * N * K;
  }
  const int m0 = mt * 128, n0 = nt * 128;
  const int t = threadIdx.x;
  const int lane = t & 63;
  const int wid = t >> 6;
  const int wm = (wid >> 1) * 64;
  const int wn = (wid & 1) * 64;
  const int l15 = lane & 15, g = lane >> 4;

  // staging: tile = 128 rows x 128B = 1024 16B-slots; wave w covers slots (w*4+c)*64+lane.
  // SOURCE slot pre-swizzled: s16' = s16 ^ ((row>>1)&7) (rule 21, 16B-granular).
  const unsigned char* asrc[4];
  const unsigned char* bsrc[4];
  int ldso[4];
  #pragma unroll
  for (int c = 0; c < 4; ++c){
    int s = (wid*4 + c)*64 + lane;
    int row = s >> 3, s16 = s & 7;
    int ssw = (s16 ^ ((row >> 1) & 7)) * 16;
    ldso[c] = s * 16;
    int r = m0 + row;
    int rc = GROUPED ? (r < cnt ? r : (cnt > 0 ? cnt - 1 : 0)) : r;
    int ar;
    if (GATHER) ar = perm[off + rc];
    else        ar = GROUPED ? off + rc : rc;
    asrc[c] = A + (size_t)ar * K + ssw;
    bsrc[c] = bp + (size_t)(n0 + row) * K + ssw;
  }

  f32x4 acc[4][4];
  #pragma unroll
  for (int i = 0; i < 4; ++i)
    #pragma unroll
    for (int j = 0; j < 4; ++j)
      #pragma unroll
      for (int r = 0; r < 4; ++r) acc[i][j][r] = 0.f;

  const int ntk = K >> 7;
  for (int tk = 0; tk < ntk; ++tk){
    const int k0 = tk << 7;
    #pragma unroll
    for (int c = 0; c < 4; ++c) gload16(asrc[c] + k0, (void*)&As[ldso[c]]);
    #pragma unroll
    for (int c = 0; c < 4; ++c) gload16(bsrc[c] + k0, (void*)&Bs[ldso[c]]);
    __syncthreads();        // drain: tile resident
    #pragma unroll
    for (int ks = 0; ks < 4; ++ks){
      long long af[4], bf[4];
      #pragma unroll
      for (int i = 0; i < 4; ++i){
        int row = wm + i * 16 + l15;
        af[i] = *(const long long*)&As[row * 128 + (((ks*4 + g) ^ (row & 14)) * 8)];
      }
      #pragma unroll
      for (int j = 0; j < 4; ++j){
        int row = wn + j * 16 + l15;
        bf[j] = *(const long long*)&Bs[row * 128 + (((ks*4 + g) ^ (row & 14)) * 8)];
      }
      #pragma unroll
      for (int i = 0; i < 4; ++i)
        #pragma unroll
        for (int j = 0; j < 4; ++j)
          acc[i][j] = __builtin_amdgcn_mfma_f32_16x16x32_fp8_fp8(af[i], bf[j], acc[i][j], 0, 0, 0);
    }
    __syncthreads();        // all reads done before next overwrite
  }

  // epilogue: D[row=(l>>4)*4+r][col=l&15] per 16x16 fragment (dtype-independent layout)
  #pragma unroll
  for (int i = 0; i < 4; ++i)
    #pragma unroll
    for (int j = 0; j < 4; ++j)
      #pragma unroll
      for (int r = 0; r < 4; ++r){
        int lr = wm + i * 16 + g * 4 + r;
        int grow = m0 + lr;
        if (GROUPED && grow >= cnt) continue;
        int gcol = n0 + wn + j * 16 + l15;
        size_t orow = GROUPED ? (size_t)(off + grow) : (size_t)grow;
        float val = acc[i][j][r];
        if (MODE == 1){
          ((float*)Cout)[orow * N + gcol] = val;
        } else if (MODE == 2){
          val *= rowscale[off + grow];
          ((unsigned short*)Cout)[orow * N + gcol] = f2bf(val);
        } else if (MODE == 6){
          float uo = __shfl_xor(val, 1);        // partner column (same row)
          if (!(l15 & 1)){
            float rv = val / (1.f + __expf(-val)) * uo;   // silu(gate)*up
            ((unsigned char*)Cout)[orow * (N >> 1) + (gcol >> 1)] = f2fp8(rv);
          }
        } else if (MODE == 7){
          int s0 = perm[grow*2], s1 = perm[grow*2+1];
          float add = bf2f(yb[(size_t)s0 * N + gcol]) + bf2f(yb[(size_t)s1 * N + gcol]);
          ((float*)Cout)[orow * N + gcol] = val + add;
        }
      }
}

// ---------------- 256x256xBK128 fp8 MFMA GEMM, T3-minimum 2-phase ----------
// LDS 128KB (2dbuf x 32KB x A,B) same as measured bf16 config; barriers per K halved.
// MODE 6 only: interleaved gate/up -> silu(even)*odd, store N/2 cols fp8.
template<int MODE, int NYT>
__global__ __launch_bounds__(512, 1) void gemm256(
    const unsigned char* __restrict__ A,
    const unsigned char* __restrict__ B,
    void* __restrict__ Cout,
    int M, int N, int K)
{
  __shared__ __align__(16) unsigned char As[2][256*128];
  __shared__ __align__(16) unsigned char Bs[2][256*128];

  const int nwg = gridDim.x;
  const int bid = blockIdx.x;
  const int wg = (bid & 7) * (nwg >> 3) + (bid >> 3);
  const int mt  = wg / NYT;
  const int ntc = wg % NYT;

  const int m0 = mt * 256, n0 = ntc * 256;
  const int t = threadIdx.x;
  const int lane = t & 63;
  const int wid = t >> 6;
  const int wm0 = (wid >> 2) * 128;
  const int wn0 = (wid & 3) * 64;
  const int l15 = lane & 15, g = lane >> 4;

  // staging: tile = 256 rows x 128B = 2048 16B-slots; thread covers slots c*512+t.
  const unsigned char* asrc[4];
  const unsigned char* bsrc[4];
  int ldst[4];
  #pragma unroll
  for (int c = 0; c < 4; ++c){
    int slot = c * 512 + t;
    int row = slot >> 3, s16 = slot & 7;
    int ssw = (s16 ^ ((row >> 1) & 7)) * 16;
    ldst[c] = slot * 16;
    asrc[c] = A + (size_t)(m0 + row) * K + ssw;
    bsrc[c] = B + (size_t)(n0 + row) * K + ssw;
  }

  f32x4 acc[8][4];
  #pragma unroll
  for (int i = 0; i < 8; ++i)
    #pragma unroll
    for (int j = 0; j < 4; ++j)
      #pragma unroll
      for (int r = 0; r < 4; ++r) acc[i][j][r] = 0.f;

  auto STAGE = [&](int buf, int kt){
    const int k0 = kt << 7;
    #pragma unroll
    for (int c = 0; c < 4; ++c) gload16(asrc[c] + k0, (void*)&As[buf][ldst[c]]);
    #pragma unroll
    for (int c = 0; c < 4; ++c) gload16(bsrc[c] + k0, (void*)&Bs[buf][ldst[c]]);
  };

  const int ntk = K >> 7;
  STAGE(0, 0);
  __syncthreads();                       // buf0 resident
  int cur = 0;
  for (int tk = 0; tk < ntk; ++tk){
    if (tk + 1 < ntk) STAGE(cur ^ 1, tk + 1);   // issue next tile FIRST (async)
    long long bfr[4][4];
    #pragma unroll
    for (int j = 0; j < 4; ++j)
      #pragma unroll
      for (int ks = 0; ks < 4; ++ks){
        int row = wn0 + j * 16 + l15;
        bfr[j][ks] = *(const long long*)&Bs[cur][row * 128 + (((ks*4 + g) ^ (row & 14)) * 8)];
      }
    #pragma unroll
    for (int mi = 0; mi < 8; ++mi){
      int row = wm0 + mi * 16 + l15;
      long long af[4];
      #pragma unroll
      for (int ks = 0; ks < 4; ++ks)
        af[ks] = *(const long long*)&As[cur][row * 128 + (((ks*4 + g) ^ (row & 14)) * 8)];
      #pragma unroll
      for (int ks = 0; ks < 4; ++ks)
        #pragma unroll
        for (int j = 0; j < 4; ++j)
          acc[mi][j] = __builtin_amdgcn_mfma_f32_16x16x32_fp8_fp8(af[ks], bfr[j][ks], acc[mi][j], 0, 0, 0);
    }
    __syncthreads();    // vmcnt(0)+barrier: my reads done, next tile resident
    cur ^= 1;
  }

  #pragma unroll
  for (int mi = 0; mi < 8; ++mi)
    #pragma unroll
    for (int j = 0; j < 4; ++j)
      #pragma unroll
      for (int r = 0; r < 4; ++r){
        int lr = wm0 + mi * 16 + g * 4 + r;
        int grow = m0 + lr;
        int gcol = n0 + wn0 + j * 16 + l15;
        float val = acc[mi][j][r];
        if (MODE == 6){
          float uo = __shfl_xor(val, 1);
          if (!(l15 & 1)){
            float rv = val / (1.f + __expf(-val)) * uo;   // silu(gate)*up
            ((unsigned char*)Cout)[(size_t)grow * (N >> 1) + (gcol >> 1)] = f2fp8(rv);
          }
        } else {
          ((float*)Cout)[(size_t)grow * N + gcol] = val;
        }
      }
}

extern "C" void kernel_launch(void* const* d_in, const int* in_sizes, int n_in,
                              void* d_out, int out_size, void* d_ws, size_t ws_size,
                              hipStream_t stream)
{
  const float* x       = (const float*)d_in[0];
  const float* gate_w  = (const float*)d_in[1];
  const float* ebias   = (const float*)d_in[2];
  const float* sh_gate = (const float*)d_in[3];
  const float* sh_up   = (const float*)d_in[4];
  const float* sh_down = (const float*)d_in[5];
  const float* ex_gate = (const float*)d_in[6];
  const float* ex_up   = (const float*)d_in[7];
  const float* ex_down = (const float*)d_in[8];
  float* out = (float*)d_out;
  (void)in_sizes; (void)n_in; (void)out_size; (void)ws_size;

  size_t o = 0;
  auto alloc = [&](size_t bytes) -> void* {
    o = (o + 255) & ~(size_t)255;
    void* p = (char*)d_ws + o;
    o += bytes;
    return p;
  };
  unsigned char* xb    = (unsigned char*)alloc((size_t)NTOK*DDIM);
  unsigned char* shguT = (unsigned char*)alloc((size_t)2*ISH*DDIM);        // interleaved g/u
  unsigned char* shdT  = (unsigned char*)alloc((size_t)DDIM*ISH);
  unsigned char* exguT = (unsigned char*)alloc((size_t)NEXP*2*IEX*DDIM);   // interleaved g/u
  unsigned char* exdT  = (unsigned char*)alloc((size_t)NEXP*DDIM*IEX);
  unsigned char* hbuf  = (unsigned char*)alloc((size_t)NTOK*KSEL*IEX);
  unsigned char* big   = (unsigned char*)alloc((size_t)NTOK*ISH);         // shared smid (fp8)
  unsigned short* ybuf = (unsigned short*)alloc((size_t)NTOK*KSEL*DDIM*2); // routed outputs bf16
  float* logits = (float*)alloc((size_t)NTOK*NEXP*4);
  int*   idxb  = (int*)alloc(NTOK*KSEL*4);
  float* gvb   = (float*)alloc(NTOK*KSEL*4);
  float* Ppart = (float*)alloc(32*16*4);
  int*   Cpart = (int*)alloc(32*16*4);
  int*   counts= (int*)alloc(64);
  int*   offs  = (int*)alloc(64);
  int*   cursor= (int*)alloc(64);
  int*   tokp  = (int*)alloc(NTOK*KSEL*4);
  float* gatep = (float*)alloc(NTOK*KSEL*4);
  int*   rslot = (int*)alloc(NTOK*KSEL*4);

  // weight prep (x convert is fused into logits_kernel)
  transpose_fp8<2,0><<<dim3(ISH/64,  DDIM/64, 1),    256, 0, stream>>>(sh_gate, shguT, DDIM, ISH);
  transpose_fp8<2,1><<<dim3(ISH/64,  DDIM/64, 1),    256, 0, stream>>>(sh_up,   shguT, DDIM, ISH);
  transpose_fp8<1,0><<<dim3(DDIM/64, ISH/64,  1),    256, 0, stream>>>(sh_down, shdT, ISH, DDIM);
  transpose_fp8<2,0><<<dim3(IEX/64,  DDIM/64, NEXP), 256, 0, stream>>>(ex_gate, exguT, DDIM, IEX);
  transpose_fp8<2,1><<<dim3(IEX/64,  DDIM/64, NEXP), 256, 0, stream>>>(ex_up,   exguT, DDIM, IEX);
  transpose_fp8<1,0><<<dim3(DDIM/64, IEX/64,  NEXP), 256, 0, stream>>>(ex_down, exdT, IEX, DDIM);

  // routing (+ fused x->fp8 convert)
  logits_kernel<<<512, 256, 0, stream>>>(x, gate_w, logits, xb);
  router_finish<<<32, 256, 0, stream>>>(logits, ebias, idxb, gvb, Ppart, Cpart);
  finalize2<<<1, 256, 0, stream>>>(Ppart, Cpart, counts, offs, cursor,
                                   out + (size_t)NTOK*DDIM);
  slot_assign<<<NTOK*KSEL/256, 256, 0, stream>>>(idxb, gvb, cursor, tokp, gatep, rslot);

  // routed experts first (stream order guarantees ybuf ready for the fused combine):
  // hbuf = silu(x@gate)*(x@up); ybuf = gate * (hbuf@down)
  gemm128<true,true,6,8><<<144*8, 256, 0, stream>>>(
      xb, exguT, hbuf, 0, 2*IEX, DDIM, counts, offs, tokp, nullptr, nullptr);
  gemm128<true,false,2,8><<<144*8, 256, 0, stream>>>(
      hbuf, exdT, ybuf, 0, DDIM, IEX, counts, offs, nullptr, gatep, nullptr);

  // shared expert: big = silu(x@sh_gate)*(x@sh_up) fused (256², grid 512);
  // out = big@sh_down + ybuf[slot0] + ybuf[slot1]  (combine fused into epilogue)
  gemm256<6,16><<<32*16, 512, 0, stream>>>(
      xb, shguT, big, NTOK, 2*ISH, DDIM);
  gemm128<false,false,7,8><<<64*8, 256, 0, stream>>>(
      big, shdT, out, NTOK, DDIM, ISH, nullptr, nullptr, rslot, nullptr, ybuf);
}

// Round 15
// 401.605 us; speedup vs baseline: 1.0089x; 1.0089x over previous
//
#include <hip/hip_runtime.h>
#include <stdint.h>

#define NTOK 8192
#define DDIM 1024
#define NEXP 16
#define KSEL 2
#define ISH 2048
#define IEX 512
#define ALPHAC 1e-4f
#define REPS 1e-9f

typedef __attribute__((ext_vector_type(8))) short short8;
typedef __attribute__((ext_vector_type(4))) float f32x4;

__device__ __forceinline__ unsigned short f2bf(float f){
  union { float f; uint32_t u; } v; v.f = f;
  uint32_t u = v.u;
  uint32_t r = (u + 0x7fffu + ((u >> 16) & 1u)) >> 16;
  return (unsigned short)r;
}
__device__ __forceinline__ float bf2f(unsigned short h){
  union { uint32_t u; float f; } v; v.u = ((uint32_t)h) << 16; return v.f;
}

// async global->LDS, 16B per lane; LDS dest = wave-uniform base + lane*16
__device__ __forceinline__ void gload16(const void* g, void* l){
  __builtin_amdgcn_global_load_lds(
      (const __attribute__((address_space(1))) void*)g,
      (__attribute__((address_space(3))) void*)l, 16, 0, 0);
}

// ------- transpose + convert: in (R,C) f32 -> out row c of length R, bf16 -------
__global__ __launch_bounds__(256) void transpose_bf16(const float* __restrict__ in,
                                                      unsigned short* __restrict__ outp,
                                                      int R, int C){
  __shared__ float tile[64][65];
  const float* ip = in + (size_t)blockIdx.z * R * C;
  unsigned short* op = outp + (size_t)blockIdx.z * R * C;
  int c0 = blockIdx.x * 64, r0 = blockIdx.y * 64;
  int t = threadIdx.x;
  int tr = t >> 4, tc = (t & 15) * 4;
  #pragma unroll
  for (int i = 0; i < 4; ++i){
    float4 v = *(const float4*)&ip[(size_t)(r0 + tr + i*16) * C + c0 + tc];
    tile[tr + i*16][tc+0] = v.x;
    tile[tr + i*16][tc+1] = v.y;
    tile[tr + i*16][tc+2] = v.z;
    tile[tr + i*16][tc+3] = v.w;
  }
  __syncthreads();
  #pragma unroll
  for (int i = 0; i < 4; ++i){
    int oc = tr + i*16;
    ushort4 w;
    w.x = f2bf(tile[tc+0][oc]);
    w.y = f2bf(tile[tc+1][oc]);
    w.z = f2bf(tile[tc+2][oc]);
    w.w = f2bf(tile[tc+3][oc]);
    *(ushort4*)&op[(size_t)(c0 + oc) * R + r0 + tc] = w;
  }
}

// ------- dual transpose: in0/in1 (R,C) f32 -> out rows (c*2+0 / c*2+1), bf16 -------
// Interleaves two sources' columns (gate/up) in one dispatch.
__global__ __launch_bounds__(256) void transpose2_bf16(const float* __restrict__ in0,
                                                       const float* __restrict__ in1,
                                                       unsigned short* __restrict__ outp,
                                                       int R, int C){
  __shared__ float tile[64][65];
  unsigned short* op = outp + (size_t)blockIdx.z * R * C * 2;
  int c0 = blockIdx.x * 64, r0 = blockIdx.y * 64;
  int t = threadIdx.x;
  int tr = t >> 4, tc = (t & 15) * 4;
  #pragma unroll
  for (int s = 0; s < 2; ++s){
    const float* ip = (s ? in1 : in0) + (size_t)blockIdx.z * R * C;
    #pragma unroll
    for (int i = 0; i < 4; ++i){
      float4 v = *(const float4*)&ip[(size_t)(r0 + tr + i*16) * C + c0 + tc];
      tile[tr + i*16][tc+0] = v.x;
      tile[tr + i*16][tc+1] = v.y;
      tile[tr + i*16][tc+2] = v.z;
      tile[tr + i*16][tc+3] = v.w;
    }
    __syncthreads();
    #pragma unroll
    for (int i = 0; i < 4; ++i){
      int oc = tr + i*16;
      ushort4 w;
      w.x = f2bf(tile[tc+0][oc]);
      w.y = f2bf(tile[tc+1][oc]);
      w.z = f2bf(tile[tc+2][oc]);
      w.w = f2bf(tile[tc+3][oc]);
      *(ushort4*)&op[(size_t)((c0 + oc) * 2 + s) * R + r0 + tc] = w;
    }
    __syncthreads();
  }
}

// ------- fused router: logits (in-register) + sigmoid/top-2/gates + P/C partials -------
// grid 512 x 256 (4 waves); each wave computes 4 tokens. ALSO writes xb (bf16 convert).
__global__ __launch_bounds__(256) void logits_router(
    const float* __restrict__ x, const float* __restrict__ gw,
    const float* __restrict__ ebias, unsigned short* __restrict__ xb,
    int* __restrict__ idxb, float* __restrict__ gvb,
    float* __restrict__ Ppart, int* __restrict__ Cpart)
{
  __shared__ float gws[16][1024];
  __shared__ float Ps[16];
  __shared__ int Cs[16];
  const int t = threadIdx.x;
  if (t < 16){ Ps[t] = 0.f; Cs[t] = 0; }
  #pragma unroll
  for (int k = 0; k < 16; ++k){
    int idx = t + k * 256;
    float4 v = ((const float4*)gw)[idx];
    int d = idx >> 2, e0 = (idx & 3) * 4;
    gws[e0+0][d] = v.x;
    gws[e0+1][d] = v.y;
    gws[e0+2][d] = v.z;
    gws[e0+3][d] = v.w;
  }
  __syncthreads();
  const int lane = t & 63, w = t >> 6;
  const int nb = blockIdx.x * 16 + w * 4;
  float pl[16]; int cl[16];
  #pragma unroll
  for (int e = 0; e < 16; ++e){ pl[e] = 0.f; cl[e] = 0; }
  for (int i = 0; i < 4; ++i){
    const int n = nb + i;
    const float4* xr = (const float4*)(x + (size_t)n * DDIM);
    ushort4* xo = (ushort4*)(xb + (size_t)n * DDIM);
    float4 xv[4];
    #pragma unroll
    for (int k = 0; k < 4; ++k) xv[k] = xr[lane + k*64];
    #pragma unroll
    for (int k = 0; k < 4; ++k){
      ushort4 ob;
      ob.x = f2bf(xv[k].x); ob.y = f2bf(xv[k].y);
      ob.z = f2bf(xv[k].z); ob.w = f2bf(xv[k].w);
      xo[lane + k*64] = ob;                 // fused f32->bf16 convert of x
    }
    float acc[16];
    #pragma unroll
    for (int e = 0; e < 16; ++e){
      float s = 0.f;
      #pragma unroll
      for (int k = 0; k < 4; ++k){
        float4 g = *(const float4*)&gws[e][(lane + k*64)*4];
        s = fmaf(xv[k].x, g.x, fmaf(xv[k].y, g.y, fmaf(xv[k].z, g.z, fmaf(xv[k].w, g.w, s))));
      }
      acc[e] = s;
    }
    #pragma unroll
    for (int m = 1; m < 64; m <<= 1)
      #pragma unroll
      for (int e = 0; e < 16; ++e)
        acc[e] += __shfl_xor(acc[e], m);
    if (lane == 0){
      float aff[16];
      float rowsum = REPS;
      #pragma unroll
      for (int e = 0; e < 16; ++e){
        aff[e] = 1.f / (1.f + __expf(-acc[e]));
        rowsum += aff[e];
      }
      float bestS = aff[0] + ebias[0], bestA = aff[0]; int i1 = 0;
      #pragma unroll
      for (int j = 1; j < 16; ++j){
        float sc = aff[j] + ebias[j];
        bool gt2 = sc > bestS;
        bestS = gt2 ? sc : bestS; bestA = gt2 ? aff[j] : bestA; i1 = gt2 ? j : i1;
      }
      float secS = -1e30f, secA = 0.f; int i2 = 0;
      #pragma unroll
      for (int j = 0; j < 16; ++j){
        float sc = aff[j] + ebias[j];
        bool ok = (j != i1) && (sc > secS);
        secS = ok ? sc : secS; secA = ok ? aff[j] : secA; i2 = ok ? j : i2;
      }
      float den = bestA + secA + REPS;
      idxb[n*2]   = i1; idxb[n*2+1] = i2;
      gvb[n*2]    = bestA / den; gvb[n*2+1] = secA / den;
      float inv = 1.f / rowsum;
      #pragma unroll
      for (int e = 0; e < 16; ++e){
        pl[e] = fmaf(aff[e], inv, pl[e]);
        cl[e] += (e == i1) + (e == i2);
      }
    }
  }
  if (lane == 0){
    #pragma unroll
    for (int e = 0; e < 16; ++e){
      atomicAdd(&Ps[e], pl[e]);
      atomicAdd(&Cs[e], cl[e]);
    }
  }
  __syncthreads();
  if (t < 16){ Ppart[blockIdx.x*16 + t] = Ps[t]; Cpart[blockIdx.x*16 + t] = Cs[t]; }
}

// ---------------- finalize: counts, offsets, cursors, balance loss, tail writes ----------------
// 512 block-partials (16 chunks x 32 blocks per thread-group).
__global__ __launch_bounds__(256) void finalize2(
    const float* __restrict__ Ppart, const int* __restrict__ Cpart,
    int* __restrict__ counts, int* __restrict__ offs, int* __restrict__ cursor,
    float* __restrict__ out_tail)
{
  __shared__ float P[16];
  __shared__ int C[16];
  int t = threadIdx.x;
  if (t < 16){ P[t] = 0.f; C[t] = 0; }
  __syncthreads();
  {
    int e = t & 15, c = t >> 4;          // 16 chunks of 32 blocks
    float p = 0.f; int cc = 0;
    for (int b = c * 32; b < c * 32 + 32; ++b){ p += Ppart[b*16 + e]; cc += Cpart[b*16 + e]; }
    atomicAdd(&P[e], p); atomicAdd(&C[e], cc);
  }
  __syncthreads();
  if (t == 0){
    int a = 0; float loss = 0.f;
    for (int i = 0; i < 16; ++i){
      offs[i] = a; cursor[i] = a; counts[i] = C[i]; a += C[i];
      loss += ((float)C[i] * (float)NEXP / (float)(KSEL * NTOK)) * (P[i] / (float)NTOK);
      out_tail[1+i] = (float)C[i];
    }
    out_tail[0] = ALPHAC * loss;
  }
}

// ---------------- slot assignment into per-expert contiguous groups ----------------
__global__ __launch_bounds__(256) void slot_assign(
    const int* __restrict__ idxb, const float* __restrict__ gvb,
    int* __restrict__ cursor, int* __restrict__ tokp, float* __restrict__ gatep,
    int* __restrict__ rslot)
{
  int i = blockIdx.x * 256 + threadIdx.x;   // (n,k) flat, 0..16383
  int e = idxb[i];
  int s = atomicAdd(&cursor[e], 1);
  tokp[s] = i >> 1;
  gatep[s] = gvb[i];
  rslot[i] = s;
}

// ---------------- 128x128xBK64 bf16 MFMA GEMM, single-buffered (m97 structure) ----------
// MODE: 1 = f32 store; 2 = bf16 * rowscale;
//       6 = interleaved gate/up -> silu(even col)*odd col, store N/2 cols bf16;
//       7 = f32 store of val + yb[perm[2*row]][col] + yb[perm[2*row+1]][col] (fused combine).
template<bool GROUPED, bool GATHER, int MODE, int NYT>
__global__ __launch_bounds__(256) void gemm128(
    const unsigned short* __restrict__ A,
    const unsigned short* __restrict__ B,
    void* __restrict__ Cout,
    int M, int N, int K,
    const int* __restrict__ counts,
    const int* __restrict__ offsets,
    const int* __restrict__ perm,
    const float* __restrict__ rowscale,
    const unsigned short* __restrict__ yb)
{
  __shared__ __align__(16) unsigned short As[128*64];
  __shared__ __align__(16) unsigned short Bs[128*64];

  const int nwg = gridDim.x;
  const int bid = blockIdx.x;
  const int wg = (bid & 7) * (nwg >> 3) + (bid >> 3);   // XCD-contiguous chunks
  const int mtl = wg / NYT;
  const int nt  = wg % NYT;

  int mt = mtl, off = 0, cnt = M;
  const unsigned short* bp = B;
  if (GROUPED){
    int acc_ = 0, e = -1;
    #pragma unroll
    for (int i = 0; i < NEXP; ++i){
      int c = counts[i]; int tt = (c + 127) >> 7;
      if (e < 0 && mtl < acc_ + tt){ e = i; mt = mtl - acc_; off = offsets[i]; cnt = c; }
      acc_ += tt;
    }
    if (e < 0) return;
    bp += (size_t)e * N * K;
  }
  const int m0 = mt * 128, n0 = nt * 128;
  const int t = threadIdx.x;
  const int lane = t & 63;
  const int wid = t >> 6;
  const int wm = (wid >> 1) * 64;
  const int wn = (wid & 1) * 64;
  const int l15 = lane & 15, g = lane >> 4;

  const unsigned short* asrc[4];
  const unsigned short* bsrc[4];
  int ldso[4];
  #pragma unroll
  for (int c = 0; c < 4; ++c){
    int s = (wid*4 + c)*64 + lane;
    int row = s >> 3, c16 = s & 7;
    int scol = (c16 ^ (row & 7)) * 8;
    ldso[c] = (wid*4 + c) * 512;
    int r = m0 + row;
    int rc = GROUPED ? (r < cnt ? r : (cnt > 0 ? cnt - 1 : 0)) : r;
    int ar;
    if (GATHER) ar = perm[off + rc];
    else        ar = GROUPED ? off + rc : rc;
    asrc[c] = A + (size_t)ar * K + scol;
    bsrc[c] = bp + (size_t)(n0 + row) * K + scol;
  }

  f32x4 acc[4][4];
  #pragma unroll
  for (int i = 0; i < 4; ++i)
    #pragma unroll
    for (int j = 0; j < 4; ++j)
      #pragma unroll
      for (int r = 0; r < 4; ++r) acc[i][j][r] = 0.f;

  const int ntk = K >> 6;
  for (int tk = 0; tk < ntk; ++tk){
    const int k0 = tk << 6;
    #pragma unroll
    for (int c = 0; c < 4; ++c) gload16(asrc[c] + k0, (void*)&As[ldso[c]]);
    #pragma unroll
    for (int c = 0; c < 4; ++c) gload16(bsrc[c] + k0, (void*)&Bs[ldso[c]]);
    __syncthreads();
    #pragma unroll
    for (int ks = 0; ks < 2; ++ks){
      short8 af[4], bf[4];
      #pragma unroll
      for (int i = 0; i < 4; ++i){
        int row = wm + i * 16 + l15;
        af[i] = *(const short8*)&As[row * 64 + (((ks*4 + g) ^ (row & 7)) * 8)];
      }
      #pragma unroll
      for (int j = 0; j < 4; ++j){
        int row = wn + j * 16 + l15;
        bf[j] = *(const short8*)&Bs[row * 64 + (((ks*4 + g) ^ (row & 7)) * 8)];
      }
      #pragma unroll
      for (int i = 0; i < 4; ++i)
        #pragma unroll
        for (int j = 0; j < 4; ++j)
          acc[i][j] = __builtin_amdgcn_mfma_f32_16x16x32_bf16(af[i], bf[j], acc[i][j], 0, 0, 0);
    }
    __syncthreads();
  }

  // epilogue: D[row=(l>>4)*4+r][col=l&15] per 16x16 fragment (m89-verified layout)
  #pragma unroll
  for (int i = 0; i < 4; ++i)
    #pragma unroll
    for (int j = 0; j < 4; ++j)
      #pragma unroll
      for (int r = 0; r < 4; ++r){
        int lr = wm + i * 16 + g * 4 + r;
        int grow = m0 + lr;
        if (GROUPED && grow >= cnt) continue;
        int gcol = n0 + wn + j * 16 + l15;
        size_t orow = GROUPED ? (size_t)(off + grow) : (size_t)grow;
        float val = acc[i][j][r];
        if (MODE == 1){
          ((float*)Cout)[orow * N + gcol] = val;
        } else if (MODE == 2){
          val *= rowscale[off + grow];
          ((unsigned short*)Cout)[orow * N + gcol] = f2bf(val);
        } else if (MODE == 6){
          float uo = __shfl_xor(val, 1);        // partner column (same row)
          if (!(l15 & 1)){
            float rv = val / (1.f + __expf(-val)) * uo;   // silu(gate)*up
            ((unsigned short*)Cout)[orow * (N >> 1) + (gcol >> 1)] = f2bf(rv);
          }
        } else if (MODE == 7){
          int s0 = perm[grow*2], s1 = perm[grow*2+1];
          float add = bf2f(yb[(size_t)s0 * N + gcol]) + bf2f(yb[(size_t)s1 * N + gcol]);
          ((float*)Cout)[orow * N + gcol] = val + add;
        }
      }
}

// ---------------- 256x256xBK64 bf16 MFMA GEMM, T3-minimum 2-phase (m230-V0) ----------
// MODE 6 only: interleaved gate/up -> silu(even)*odd, store N/2 cols bf16.
template<int MODE, int NYT>
__global__ __launch_bounds__(512, 1) void gemm256(
    const unsigned short* __restrict__ A,
    const unsigned short* __restrict__ B,
    void* __restrict__ Cout,
    int M, int N, int K)
{
  __shared__ __align__(16) unsigned short As[2][256*64];
  __shared__ __align__(16) unsigned short Bs[2][256*64];

  const int nwg = gridDim.x;
  const int bid = blockIdx.x;
  const int wg = (bid & 7) * (nwg >> 3) + (bid >> 3);
  const int mt  = wg / NYT;
  const int ntc = wg % NYT;

  const int m0 = mt * 256, n0 = ntc * 256;
  const int t = threadIdx.x;
  const int lane = t & 63;
  const int wid = t >> 6;
  const int wm0 = (wid >> 2) * 128;
  const int wn0 = (wid & 3) * 64;
  const int l15 = lane & 15, g = lane >> 4;

  const unsigned short* asrc[4];
  const unsigned short* bsrc[4];
  int ldst[4];
  #pragma unroll
  for (int c = 0; c < 4; ++c){
    int slot = c * 512 + t;
    int row = slot >> 3, c16 = slot & 7;
    int scol = (c16 ^ (row & 7)) * 8;
    ldst[c] = slot * 8;
    asrc[c] = A + (size_t)(m0 + row) * K + scol;
    bsrc[c] = B + (size_t)(n0 + row) * K + scol;
  }

  f32x4 acc[8][4];
  #pragma unroll
  for (int i = 0; i < 8; ++i)
    #pragma unroll
    for (int j = 0; j < 4; ++j)
      #pragma unroll
      for (int r = 0; r < 4; ++r) acc[i][j][r] = 0.f;

  auto STAGE = [&](int buf, int kt){
    const int k0 = kt << 6;
    #pragma unroll
    for (int c = 0; c < 4; ++c) gload16(asrc[c] + k0, (void*)&As[buf][ldst[c]]);
    #pragma unroll
    for (int c = 0; c < 4; ++c) gload16(bsrc[c] + k0, (void*)&Bs[buf][ldst[c]]);
  };

  const int ntk = K >> 6;
  STAGE(0, 0);
  __syncthreads();
  int cur = 0;
  for (int tk = 0; tk < ntk; ++tk){
    if (tk + 1 < ntk) STAGE(cur ^ 1, tk + 1);   // issue next tile FIRST (async)
    short8 bfr[4][2];
    #pragma unroll
    for (int j = 0; j < 4; ++j)
      #pragma unroll
      for (int ks = 0; ks < 2; ++ks){
        int row = wn0 + j * 16 + l15;
        bfr[j][ks] = *(const short8*)&Bs[cur][row * 64 + (((ks*4 + g) ^ (row & 7)) * 8)];
      }
    #pragma unroll
    for (int mi = 0; mi < 8; ++mi){
      int row = wm0 + mi * 16 + l15;
      short8 af0 = *(const short8*)&As[cur][row * 64 + (((0 + g) ^ (row & 7)) * 8)];
      short8 af1 = *(const short8*)&As[cur][row * 64 + (((4 + g) ^ (row & 7)) * 8)];
      #pragma unroll
      for (int j = 0; j < 4; ++j)
        acc[mi][j] = __builtin_amdgcn_mfma_f32_16x16x32_bf16(af0, bfr[j][0], acc[mi][j], 0, 0, 0);
      #pragma unroll
      for (int j = 0; j < 4; ++j)
        acc[mi][j] = __builtin_amdgcn_mfma_f32_16x16x32_bf16(af1, bfr[j][1], acc[mi][j], 0, 0, 0);
    }
    __syncthreads();
    cur ^= 1;
  }

  #pragma unroll
  for (int mi = 0; mi < 8; ++mi)
    #pragma unroll
    for (int j = 0; j < 4; ++j)
      #pragma unroll
      for (int r = 0; r < 4; ++r){
        int lr = wm0 + mi * 16 + g * 4 + r;
        int grow = m0 + lr;
        int gcol = n0 + wn0 + j * 16 + l15;
        float val = acc[mi][j][r];
        if (MODE == 6){
          float uo = __shfl_xor(val, 1);
          if (!(l15 & 1)){
            float rv = val / (1.f + __expf(-val)) * uo;   // silu(gate)*up
            ((unsigned short*)Cout)[(size_t)grow * (N >> 1) + (gcol >> 1)] = f2bf(rv);
          }
        } else {
          ((float*)Cout)[(size_t)grow * N + gcol] = val;
        }
      }
}

extern "C" void kernel_launch(void* const* d_in, const int* in_sizes, int n_in,
                              void* d_out, int out_size, void* d_ws, size_t ws_size,
                              hipStream_t stream)
{
  const float* x       = (const float*)d_in[0];
  const float* gate_w  = (const float*)d_in[1];
  const float* ebias   = (const float*)d_in[2];
  const float* sh_gate = (const float*)d_in[3];
  const float* sh_up   = (const float*)d_in[4];
  const float* sh_down = (const float*)d_in[5];
  const float* ex_gate = (const float*)d_in[6];
  const float* ex_up   = (const float*)d_in[7];
  const float* ex_down = (const float*)d_in[8];
  float* out = (float*)d_out;
  (void)in_sizes; (void)n_in; (void)out_size; (void)ws_size;

  size_t o = 0;
  auto alloc = [&](size_t bytes) -> void* {
    o = (o + 255) & ~(size_t)255;
    void* p = (char*)d_ws + o;
    o += bytes;
    return p;
  };
  unsigned short* xb    = (unsigned short*)alloc((size_t)NTOK*DDIM*2);
  unsigned short* shguT = (unsigned short*)alloc((size_t)2*ISH*DDIM*2);       // interleaved g/u
  unsigned short* shdT  = (unsigned short*)alloc((size_t)DDIM*ISH*2);
  unsigned short* exguT = (unsigned short*)alloc((size_t)NEXP*2*IEX*DDIM*2);  // interleaved g/u
  unsigned short* exdT  = (unsigned short*)alloc((size_t)NEXP*DDIM*IEX*2);
  unsigned short* hbuf  = (unsigned short*)alloc((size_t)NTOK*KSEL*IEX*2);
  unsigned short* big   = (unsigned short*)alloc((size_t)NTOK*ISH*2);        // shared smid
  unsigned short* ybuf  = (unsigned short*)alloc((size_t)NTOK*KSEL*DDIM*2);  // routed outputs
  int*   idxb  = (int*)alloc(NTOK*KSEL*4);
  float* gvb   = (float*)alloc(NTOK*KSEL*4);
  float* Ppart = (float*)alloc(512*16*4);
  int*   Cpart = (int*)alloc(512*16*4);
  int*   counts= (int*)alloc(64);
  int*   offs  = (int*)alloc(64);
  int*   cursor= (int*)alloc(64);
  int*   tokp  = (int*)alloc(NTOK*KSEL*4);
  float* gatep = (float*)alloc(NTOK*KSEL*4);
  int*   rslot = (int*)alloc(NTOK*KSEL*4);

  // weight prep (x convert fused into router; gate/up pairs merged into one dispatch)
  transpose2_bf16<<<dim3(ISH/64, DDIM/64, 1),    256, 0, stream>>>(sh_gate, sh_up, shguT, DDIM, ISH);
  transpose_bf16<<<dim3(DDIM/64, ISH/64, 1),     256, 0, stream>>>(sh_down, shdT, ISH, DDIM);
  transpose2_bf16<<<dim3(IEX/64, DDIM/64, NEXP), 256, 0, stream>>>(ex_gate, ex_up, exguT, DDIM, IEX);
  transpose_bf16<<<dim3(DDIM/64, IEX/64, NEXP),  256, 0, stream>>>(ex_down, exdT, IEX, DDIM);

  // routing: fused logits + sigmoid/top-2/gates + P/C partials (+ x->bf16 convert)
  logits_router<<<512, 256, 0, stream>>>(x, gate_w, ebias, xb, idxb, gvb, Ppart, Cpart);
  finalize2<<<1, 256, 0, stream>>>(Ppart, Cpart, counts, offs, cursor,
                                   out + (size_t)NTOK*DDIM);
  slot_assign<<<NTOK*KSEL/256, 256, 0, stream>>>(idxb, gvb, cursor, tokp, gatep, rslot);

  // routed experts first (stream order guarantees ybuf ready for the fused combine):
  // hbuf = silu(x@gate)*(x@up); ybuf = gate * (hbuf@down)
  gemm128<true,true,6,8><<<144*8, 256, 0, stream>>>(
      xb, exguT, hbuf, 0, 2*IEX, DDIM, counts, offs, tokp, nullptr, nullptr);
  gemm128<true,false,2,8><<<144*8, 256, 0, stream>>>(
      hbuf, exdT, ybuf, 0, DDIM, IEX, counts, offs, nullptr, gatep, nullptr);

  // shared expert: big = silu(x@sh_gate)*(x@sh_up) fused (256², grid 512);
  // out = big@sh_down + ybuf[slot0] + ybuf[slot1]  (combine fused into epilogue)
  gemm256<6,16><<<32*16, 512, 0, stream>>>(
      xb, shguT, big, NTOK, 2*ISH, DDIM);
  gemm128<false,false,7,8><<<64*8, 256, 0, stream>>>(
      big, shdT, out, NTOK, DDIM, ISH, nullptr, nullptr, rslot, nullptr, ybuf);
}

// Round 16
// 379.497 us; speedup vs baseline: 1.0677x; 1.0583x over previous
//
#include <hip/hip_runtime.h>
#include <stdint.h>

#define NTOK 8192
#define DDIM 1024
#define NEXP 16
#define KSEL 2
#define ISH 2048
#define IEX 512
#define ALPHAC 1e-4f
#define REPS 1e-9f

typedef __attribute__((ext_vector_type(8))) short short8;
typedef __attribute__((ext_vector_type(4))) float f32x4;

__device__ __forceinline__ unsigned short f2bf(float f){
  union { float f; uint32_t u; } v; v.f = f;
  uint32_t u = v.u;
  uint32_t r = (u + 0x7fffu + ((u >> 16) & 1u)) >> 16;
  return (unsigned short)r;
}
__device__ __forceinline__ float bf2f(unsigned short h){
  union { uint32_t u; float f; } v; v.u = ((uint32_t)h) << 16; return v.f;
}

// async global->LDS, 16B per lane; LDS dest = wave-uniform base + lane*16
__device__ __forceinline__ void gload16(const void* g, void* l){
  __builtin_amdgcn_global_load_lds(
      (const __attribute__((address_space(1))) void*)g,
      (__attribute__((address_space(3))) void*)l, 16, 0, 0);
}

// ------- transpose + convert: in (R,C) f32 -> out row (c*RM+RO) of length R, bf16 -------
template<int RM, int RO>
__global__ __launch_bounds__(256) void transpose_bf16(const float* __restrict__ in,
                                                      unsigned short* __restrict__ outp,
                                                      int R, int C){
  __shared__ float tile[64][65];
  const float* ip = in + (size_t)blockIdx.z * R * C;
  unsigned short* op = outp + (size_t)blockIdx.z * R * C * RM;
  int c0 = blockIdx.x * 64, r0 = blockIdx.y * 64;
  int t = threadIdx.x;
  int tr = t >> 4, tc = (t & 15) * 4;
  #pragma unroll
  for (int i = 0; i < 4; ++i){
    float4 v = *(const float4*)&ip[(size_t)(r0 + tr + i*16) * C + c0 + tc];
    tile[tr + i*16][tc+0] = v.x;
    tile[tr + i*16][tc+1] = v.y;
    tile[tr + i*16][tc+2] = v.z;
    tile[tr + i*16][tc+3] = v.w;
  }
  __syncthreads();
  #pragma unroll
  for (int i = 0; i < 4; ++i){
    int oc = tr + i*16;
    ushort4 w;
    w.x = f2bf(tile[tc+0][oc]);
    w.y = f2bf(tile[tc+1][oc]);
    w.z = f2bf(tile[tc+2][oc]);
    w.w = f2bf(tile[tc+3][oc]);
    *(ushort4*)&op[(size_t)((c0 + oc) * RM + RO) * R + r0 + tc] = w;
  }
}

// ------- router stage 1: fp32 logits = x @ gw, wave-per-token; ALSO writes xb (bf16) -------
__global__ __launch_bounds__(256) void logits_kernel(
    const float* __restrict__ x, const float* __restrict__ gw,
    float* __restrict__ logits, unsigned short* __restrict__ xb)
{
  __shared__ float gws[16][1024];
  const int t = threadIdx.x;
  #pragma unroll
  for (int k = 0; k < 16; ++k){
    int idx = t + k * 256;
    float4 v = ((const float4*)gw)[idx];
    int d = idx >> 2, e0 = (idx & 3) * 4;
    gws[e0+0][d] = v.x;
    gws[e0+1][d] = v.y;
    gws[e0+2][d] = v.z;
    gws[e0+3][d] = v.w;
  }
  __syncthreads();
  const int lane = t & 63, w = t >> 6;
  const int nb = blockIdx.x * 16 + w * 4;
  for (int i = 0; i < 4; ++i){
    const int n = nb + i;
    const float4* xr = (const float4*)(x + (size_t)n * DDIM);
    ushort4* xo = (ushort4*)(xb + (size_t)n * DDIM);
    float4 xv[4];
    #pragma unroll
    for (int k = 0; k < 4; ++k) xv[k] = xr[lane + k*64];
    #pragma unroll
    for (int k = 0; k < 4; ++k){
      ushort4 ob;
      ob.x = f2bf(xv[k].x); ob.y = f2bf(xv[k].y);
      ob.z = f2bf(xv[k].z); ob.w = f2bf(xv[k].w);
      xo[lane + k*64] = ob;                 // fused f32->bf16 convert of x
    }
    float acc[16];
    #pragma unroll
    for (int e = 0; e < 16; ++e){
      float s = 0.f;
      #pragma unroll
      for (int k = 0; k < 4; ++k){
        float4 g = *(const float4*)&gws[e][(lane + k*64)*4];
        s = fmaf(xv[k].x, g.x, fmaf(xv[k].y, g.y, fmaf(xv[k].z, g.z, fmaf(xv[k].w, g.w, s))));
      }
      acc[e] = s;
    }
    #pragma unroll
    for (int m = 1; m < 64; m <<= 1)
      #pragma unroll
      for (int e = 0; e < 16; ++e)
        acc[e] += __shfl_xor(acc[e], m);
    if (lane == 0){
      float4* op = (float4*)(logits + (size_t)n * 16);
      op[0] = make_float4(acc[0],  acc[1],  acc[2],  acc[3]);
      op[1] = make_float4(acc[4],  acc[5],  acc[6],  acc[7]);
      op[2] = make_float4(acc[8],  acc[9],  acc[10], acc[11]);
      op[3] = make_float4(acc[12], acc[13], acc[14], acc[15]);
    }
  }
}

// ---------------- router stage 2: sigmoid, top-2, gates, P/C partials ----------------
__global__ __launch_bounds__(256) void router_finish(
    const float* __restrict__ logits, const float* __restrict__ ebias,
    int* __restrict__ idxb, float* __restrict__ gvb,
    float* __restrict__ Ppart, int* __restrict__ Cpart)
{
  __shared__ float Ps[16];
  __shared__ int Cs[16];
  const int t = threadIdx.x;
  if (t < 16){ Ps[t] = 0.f; Cs[t] = 0; }
  __syncthreads();
  const int lane = t & 63;
  const int n = blockIdx.x * 256 + t;
  const float4* lp = (const float4*)(logits + (size_t)n * 16);
  float4 a0 = lp[0], a1 = lp[1], a2 = lp[2], a3 = lp[3];
  float aff[16];
  aff[0]=a0.x; aff[1]=a0.y; aff[2]=a0.z; aff[3]=a0.w;
  aff[4]=a1.x; aff[5]=a1.y; aff[6]=a1.z; aff[7]=a1.w;
  aff[8]=a2.x; aff[9]=a2.y; aff[10]=a2.z; aff[11]=a2.w;
  aff[12]=a3.x; aff[13]=a3.y; aff[14]=a3.z; aff[15]=a3.w;
  float rowsum = REPS;
  #pragma unroll
  for (int e = 0; e < 16; ++e){
    aff[e] = 1.f / (1.f + __expf(-aff[e]));
    rowsum += aff[e];
  }
  float bj[16];
  #pragma unroll
  for (int e = 0; e < 16; ++e) bj[e] = ebias[e];
  float bestS = aff[0] + bj[0], bestA = aff[0]; int i1 = 0;
  #pragma unroll
  for (int j = 1; j < 16; ++j){
    float sc = aff[j] + bj[j];
    bool gt2 = sc > bestS;
    bestS = gt2 ? sc : bestS; bestA = gt2 ? aff[j] : bestA; i1 = gt2 ? j : i1;
  }
  float secS = -1e30f, secA = 0.f; int i2 = 0;
  #pragma unroll
  for (int j = 0; j < 16; ++j){
    float sc = aff[j] + bj[j];
    bool ok = (j != i1) && (sc > secS);
    secS = ok ? sc : secS; secA = ok ? aff[j] : secA; i2 = ok ? j : i2;
  }
  float den = bestA + secA + REPS;
  idxb[n*2]   = i1; idxb[n*2+1] = i2;
  gvb[n*2]    = bestA / den; gvb[n*2+1] = secA / den;

  float inv = 1.f / rowsum;
  float pv[16]; int cv[16];
  #pragma unroll
  for (int e = 0; e < 16; ++e){
    pv[e] = aff[e] * inv;
    cv[e] = (e == i1) + (e == i2);
  }
  #pragma unroll
  for (int m = 1; m < 64; m <<= 1)
    #pragma unroll
    for (int e = 0; e < 16; ++e){
      pv[e] += __shfl_xor(pv[e], m);
      cv[e] += __shfl_xor(cv[e], m);
    }
  if (lane == 0){
    #pragma unroll
    for (int e = 0; e < 16; ++e){
      atomicAdd(&Ps[e], pv[e]);
      atomicAdd(&Cs[e], cv[e]);
    }
  }
  __syncthreads();
  if (t < 16){ Ppart[blockIdx.x*16 + t] = Ps[t]; Cpart[blockIdx.x*16 + t] = Cs[t]; }
}

// ---------------- finalize: counts, offsets, cursors, balance loss, tail writes ----------------
__global__ __launch_bounds__(256) void finalize2(
    const float* __restrict__ Ppart, const int* __restrict__ Cpart,
    int* __restrict__ counts, int* __restrict__ offs, int* __restrict__ cursor,
    float* __restrict__ out_tail)
{
  __shared__ float P[16];
  __shared__ int C[16];
  int t = threadIdx.x;
  if (t < 16){ P[t] = 0.f; C[t] = 0; }
  __syncthreads();
  if (t < 32){
    int e = t & 15, c = t >> 4;
    float p = 0.f; int cc = 0;
    for (int b = c * 16; b < c * 16 + 16; ++b){ p += Ppart[b*16 + e]; cc += Cpart[b*16 + e]; }
    atomicAdd(&P[e], p); atomicAdd(&C[e], cc);
  }
  __syncthreads();
  if (t == 0){
    int a = 0; float loss = 0.f;
    for (int i = 0; i < 16; ++i){
      offs[i] = a; cursor[i] = a; counts[i] = C[i]; a += C[i];
      loss += ((float)C[i] * (float)NEXP / (float)(KSEL * NTOK)) * (P[i] / (float)NTOK);
      out_tail[1+i] = (float)C[i];
    }
    out_tail[0] = ALPHAC * loss;
  }
}

// ---------------- slot assignment into per-expert contiguous groups ----------------
__global__ __launch_bounds__(256) void slot_assign(
    const int* __restrict__ idxb, const float* __restrict__ gvb,
    int* __restrict__ cursor, int* __restrict__ tokp, float* __restrict__ gatep,
    int* __restrict__ rslot)
{
  int i = blockIdx.x * 256 + threadIdx.x;   // (n,k) flat, 0..16383
  int e = idxb[i];
  int s = atomicAdd(&cursor[e], 1);
  tokp[s] = i >> 1;
  gatep[s] = gvb[i];
  rslot[i] = s;
}

// ---------------- 128x128xBK64 bf16 MFMA GEMM, single-buffered (m97 structure) ----------
// MODE: 1 = f32 store; 2 = bf16 * rowscale;
//       6 = interleaved gate/up -> silu(even col)*odd col, store N/2 cols bf16;
//       7 = f32 store of val + yb[perm[2*row]][col] + yb[perm[2*row+1]][col] (fused combine).
template<bool GROUPED, bool GATHER, int MODE, int NYT>
__global__ __launch_bounds__(256) void gemm128(
    const unsigned short* __restrict__ A,
    const unsigned short* __restrict__ B,
    void* __restrict__ Cout,
    int M, int N, int K,
    const int* __restrict__ counts,
    const int* __restrict__ offsets,
    const int* __restrict__ perm,
    const float* __restrict__ rowscale,
    const unsigned short* __restrict__ yb)
{
  __shared__ __align__(16) unsigned short As[128*64];
  __shared__ __align__(16) unsigned short Bs[128*64];

  const int nwg = gridDim.x;
  const int bid = blockIdx.x;
  const int wg = (bid & 7) * (nwg >> 3) + (bid >> 3);   // XCD-contiguous chunks
  const int mtl = wg / NYT;
  const int nt  = wg % NYT;

  int mt = mtl, off = 0, cnt = M;
  const unsigned short* bp = B;
  if (GROUPED){
    int acc_ = 0, e = -1;
    #pragma unroll
    for (int i = 0; i < NEXP; ++i){
      int c = counts[i]; int tt = (c + 127) >> 7;
      if (e < 0 && mtl < acc_ + tt){ e = i; mt = mtl - acc_; off = offsets[i]; cnt = c; }
      acc_ += tt;
    }
    if (e < 0) return;
    bp += (size_t)e * N * K;
  }
  const int m0 = mt * 128, n0 = nt * 128;
  const int t = threadIdx.x;
  const int lane = t & 63;
  const int wid = t >> 6;
  const int wm = (wid >> 1) * 64;
  const int wn = (wid & 1) * 64;
  const int l15 = lane & 15, g = lane >> 4;

  const unsigned short* asrc[4];
  const unsigned short* bsrc[4];
  int ldso[4];
  #pragma unroll
  for (int c = 0; c < 4; ++c){
    int s = (wid*4 + c)*64 + lane;
    int row = s >> 3, c16 = s & 7;
    int scol = (c16 ^ (row & 7)) * 8;
    ldso[c] = (wid*4 + c) * 512;
    int r = m0 + row;
    int rc = GROUPED ? (r < cnt ? r : (cnt > 0 ? cnt - 1 : 0)) : r;
    int ar;
    if (GATHER) ar = perm[off + rc];
    else        ar = GROUPED ? off + rc : rc;
    asrc[c] = A + (size_t)ar * K + scol;
    bsrc[c] = bp + (size_t)(n0 + row) * K + scol;
  }

  f32x4 acc[4][4];
  #pragma unroll
  for (int i = 0; i < 4; ++i)
    #pragma unroll
    for (int j = 0; j < 4; ++j)
      #pragma unroll
      for (int r = 0; r < 4; ++r) acc[i][j][r] = 0.f;

  const int ntk = K >> 6;
  for (int tk = 0; tk < ntk; ++tk){
    const int k0 = tk << 6;
    #pragma unroll
    for (int c = 0; c < 4; ++c) gload16(asrc[c] + k0, (void*)&As[ldso[c]]);
    #pragma unroll
    for (int c = 0; c < 4; ++c) gload16(bsrc[c] + k0, (void*)&Bs[ldso[c]]);
    __syncthreads();
    #pragma unroll
    for (int ks = 0; ks < 2; ++ks){
      short8 af[4], bf[4];
      #pragma unroll
      for (int i = 0; i < 4; ++i){
        int row = wm + i * 16 + l15;
        af[i] = *(const short8*)&As[row * 64 + (((ks*4 + g) ^ (row & 7)) * 8)];
      }
      #pragma unroll
      for (int j = 0; j < 4; ++j){
        int row = wn + j * 16 + l15;
        bf[j] = *(const short8*)&Bs[row * 64 + (((ks*4 + g) ^ (row & 7)) * 8)];
      }
      #pragma unroll
      for (int i = 0; i < 4; ++i)
        #pragma unroll
        for (int j = 0; j < 4; ++j)
          acc[i][j] = __builtin_amdgcn_mfma_f32_16x16x32_bf16(af[i], bf[j], acc[i][j], 0, 0, 0);
    }
    __syncthreads();
  }

  // epilogue: D[row=(l>>4)*4+r][col=l&15] per 16x16 fragment (m89-verified layout)
  #pragma unroll
  for (int i = 0; i < 4; ++i)
    #pragma unroll
    for (int j = 0; j < 4; ++j)
      #pragma unroll
      for (int r = 0; r < 4; ++r){
        int lr = wm + i * 16 + g * 4 + r;
        int grow = m0 + lr;
        if (GROUPED && grow >= cnt) continue;
        int gcol = n0 + wn + j * 16 + l15;
        size_t orow = GROUPED ? (size_t)(off + grow) : (size_t)grow;
        float val = acc[i][j][r];
        if (MODE == 1){
          ((float*)Cout)[orow * N + gcol] = val;
        } else if (MODE == 2){
          val *= rowscale[off + grow];
          ((unsigned short*)Cout)[orow * N + gcol] = f2bf(val);
        } else if (MODE == 6){
          float uo = __shfl_xor(val, 1);        // partner column (same row)
          if (!(l15 & 1)){
            float rv = val / (1.f + __expf(-val)) * uo;   // silu(gate)*up
            ((unsigned short*)Cout)[orow * (N >> 1) + (gcol >> 1)] = f2bf(rv);
          }
        } else if (MODE == 7){
          int s0 = perm[grow*2], s1 = perm[grow*2+1];
          float add = bf2f(yb[(size_t)s0 * N + gcol]) + bf2f(yb[(size_t)s1 * N + gcol]);
          ((float*)Cout)[orow * N + gcol] = val + add;
        }
      }
}

// ---------------- 256x256xBK64 bf16 MFMA GEMM, T3-minimum 2-phase (m230-V0) ----------
// MODE 6 only: interleaved gate/up -> silu(even)*odd, store N/2 cols bf16.
template<int MODE, int NYT>
__global__ __launch_bounds__(512, 1) void gemm256(
    const unsigned short* __restrict__ A,
    const unsigned short* __restrict__ B,
    void* __restrict__ Cout,
    int M, int N, int K)
{
  __shared__ __align__(16) unsigned short As[2][256*64];
  __shared__ __align__(16) unsigned short Bs[2][256*64];

  const int nwg = gridDim.x;
  const int bid = blockIdx.x;
  const int wg = (bid & 7) * (nwg >> 3) + (bid >> 3);
  const int mt  = wg / NYT;
  const int ntc = wg % NYT;

  const int m0 = mt * 256, n0 = ntc * 256;
  const int t = threadIdx.x;
  const int lane = t & 63;
  const int wid = t >> 6;
  const int wm0 = (wid >> 2) * 128;
  const int wn0 = (wid & 3) * 64;
  const int l15 = lane & 15, g = lane >> 4;

  const unsigned short* asrc[4];
  const unsigned short* bsrc[4];
  int ldst[4];
  #pragma unroll
  for (int c = 0; c < 4; ++c){
    int slot = c * 512 + t;
    int row = slot >> 3, c16 = slot & 7;
    int scol = (c16 ^ (row & 7)) * 8;
    ldst[c] = slot * 8;
    asrc[c] = A + (size_t)(m0 + row) * K + scol;
    bsrc[c] = B + (size_t)(n0 + row) * K + scol;
  }

  f32x4 acc[8][4];
  #pragma unroll
  for (int i = 0; i < 8; ++i)
    #pragma unroll
    for (int j = 0; j < 4; ++j)
      #pragma unroll
      for (int r = 0; r < 4; ++r) acc[i][j][r] = 0.f;

  auto STAGE = [&](int buf, int kt){
    const int k0 = kt << 6;
    #pragma unroll
    for (int c = 0; c < 4; ++c) gload16(asrc[c] + k0, (void*)&As[buf][ldst[c]]);
    #pragma unroll
    for (int c = 0; c < 4; ++c) gload16(bsrc[c] + k0, (void*)&Bs[buf][ldst[c]]);
  };

  const int ntk = K >> 6;
  STAGE(0, 0);
  __syncthreads();
  int cur = 0;
  for (int tk = 0; tk < ntk; ++tk){
    if (tk + 1 < ntk) STAGE(cur ^ 1, tk + 1);   // issue next tile FIRST (async)
    short8 bfr[4][2];
    #pragma unroll
    for (int j = 0; j < 4; ++j)
      #pragma unroll
      for (int ks = 0; ks < 2; ++ks){
        int row = wn0 + j * 16 + l15;
        bfr[j][ks] = *(const short8*)&Bs[cur][row * 64 + (((ks*4 + g) ^ (row & 7)) * 8)];
      }
    #pragma unroll
    for (int mi = 0; mi < 8; ++mi){
      int row = wm0 + mi * 16 + l15;
      short8 af0 = *(const short8*)&As[cur][row * 64 + (((0 + g) ^ (row & 7)) * 8)];
      short8 af1 = *(const short8*)&As[cur][row * 64 + (((4 + g) ^ (row & 7)) * 8)];
      #pragma unroll
      for (int j = 0; j < 4; ++j)
        acc[mi][j] = __builtin_amdgcn_mfma_f32_16x16x32_bf16(af0, bfr[j][0], acc[mi][j], 0, 0, 0);
      #pragma unroll
      for (int j = 0; j < 4; ++j)
        acc[mi][j] = __builtin_amdgcn_mfma_f32_16x16x32_bf16(af1, bfr[j][1], acc[mi][j], 0, 0, 0);
    }
    __syncthreads();
    cur ^= 1;
  }

  #pragma unroll
  for (int mi = 0; mi < 8; ++mi)
    #pragma unroll
    for (int j = 0; j < 4; ++j)
      #pragma unroll
      for (int r = 0; r < 4; ++r){
        int lr = wm0 + mi * 16 + g * 4 + r;
        int grow = m0 + lr;
        int gcol = n0 + wn0 + j * 16 + l15;
        float val = acc[mi][j][r];
        if (MODE == 6){
          float uo = __shfl_xor(val, 1);
          if (!(l15 & 1)){
            float rv = val / (1.f + __expf(-val)) * uo;   // silu(gate)*up
            ((unsigned short*)Cout)[(size_t)grow * (N >> 1) + (gcol >> 1)] = f2bf(rv);
          }
        } else {
          ((float*)Cout)[(size_t)grow * N + gcol] = val;
        }
      }
}

extern "C" void kernel_launch(void* const* d_in, const int* in_sizes, int n_in,
                              void* d_out, int out_size, void* d_ws, size_t ws_size,
                              hipStream_t stream)
{
  const float* x       = (const float*)d_in[0];
  const float* gate_w  = (const float*)d_in[1];
  const float* ebias   = (const float*)d_in[2];
  const float* sh_gate = (const float*)d_in[3];
  const float* sh_up   = (const float*)d_in[4];
  const float* sh_down = (const float*)d_in[5];
  const float* ex_gate = (const float*)d_in[6];
  const float* ex_up   = (const float*)d_in[7];
  const float* ex_down = (const float*)d_in[8];
  float* out = (float*)d_out;
  (void)in_sizes; (void)n_in; (void)out_size; (void)ws_size;

  size_t o = 0;
  auto alloc = [&](size_t bytes) -> void* {
    o = (o + 255) & ~(size_t)255;
    void* p = (char*)d_ws + o;
    o += bytes;
    return p;
  };
  unsigned short* xb    = (unsigned short*)alloc((size_t)NTOK*DDIM*2);
  unsigned short* shguT = (unsigned short*)alloc((size_t)2*ISH*DDIM*2);       // interleaved g/u
  unsigned short* shdT  = (unsigned short*)alloc((size_t)DDIM*ISH*2);
  unsigned short* exguT = (unsigned short*)alloc((size_t)NEXP*2*IEX*DDIM*2);  // interleaved g/u
  unsigned short* exdT  = (unsigned short*)alloc((size_t)NEXP*DDIM*IEX*2);
  unsigned short* hbuf  = (unsigned short*)alloc((size_t)NTOK*KSEL*IEX*2);
  unsigned short* big   = (unsigned short*)alloc((size_t)NTOK*ISH*2);        // shared smid
  unsigned short* ybuf  = (unsigned short*)alloc((size_t)NTOK*KSEL*DDIM*2);  // routed outputs
  float* logits = (float*)alloc((size_t)NTOK*NEXP*4);
  int*   idxb  = (int*)alloc(NTOK*KSEL*4);
  float* gvb   = (float*)alloc(NTOK*KSEL*4);
  float* Ppart = (float*)alloc(32*16*4);
  int*   Cpart = (int*)alloc(32*16*4);
  int*   counts= (int*)alloc(64);
  int*   offs  = (int*)alloc(64);
  int*   cursor= (int*)alloc(64);
  int*   tokp  = (int*)alloc(NTOK*KSEL*4);
  float* gatep = (float*)alloc(NTOK*KSEL*4);
  int*   rslot = (int*)alloc(NTOK*KSEL*4);

  // weight prep (x convert is fused into logits_kernel)
  transpose_bf16<2,0><<<dim3(ISH/64,  DDIM/64, 1),    256, 0, stream>>>(sh_gate, shguT, DDIM, ISH);
  transpose_bf16<2,1><<<dim3(ISH/64,  DDIM/64, 1),    256, 0, stream>>>(sh_up,   shguT, DDIM, ISH);
  transpose_bf16<1,0><<<dim3(DDIM/64, ISH/64,  1),    256, 0, stream>>>(sh_down, shdT, ISH, DDIM);
  transpose_bf16<2,0><<<dim3(IEX/64,  DDIM/64, NEXP), 256, 0, stream>>>(ex_gate, exguT, DDIM, IEX);
  transpose_bf16<2,1><<<dim3(IEX/64,  DDIM/64, NEXP), 256, 0, stream>>>(ex_up,   exguT, DDIM, IEX);
  transpose_bf16<1,0><<<dim3(DDIM/64, IEX/64,  NEXP), 256, 0, stream>>>(ex_down, exdT, IEX, DDIM);

  // routing (+ fused x->bf16 convert)
  logits_kernel<<<512, 256, 0, stream>>>(x, gate_w, logits, xb);
  router_finish<<<32, 256, 0, stream>>>(logits, ebias, idxb, gvb, Ppart, Cpart);
  finalize2<<<1, 256, 0, stream>>>(Ppart, Cpart, counts, offs, cursor,
                                   out + (size_t)NTOK*DDIM);
  slot_assign<<<NTOK*KSEL/256, 256, 0, stream>>>(idxb, gvb, cursor, tokp, gatep, rslot);

  // routed experts first (stream order guarantees ybuf ready for the fused combine):
  // hbuf = silu(x@gate)*(x@up); ybuf = gate * (hbuf@down)
  gemm128<true,true,6,8><<<144*8, 256, 0, stream>>>(
      xb, exguT, hbuf, 0, 2*IEX, DDIM, counts, offs, tokp, nullptr, nullptr);
  gemm128<true,false,2,8><<<144*8, 256, 0, stream>>>(
      hbuf, exdT, ybuf, 0, DDIM, IEX, counts, offs, nullptr, gatep, nullptr);

  // shared expert: big = silu(x@sh_gate)*(x@sh_up) fused (256², grid 512);
  // out = big@sh_down + ybuf[slot0] + ybuf[slot1]  (combine fused into epilogue)
  gemm256<6,16><<<32*16, 512, 0, stream>>>(
      xb, shguT, big, NTOK, 2*ISH, DDIM);
  gemm128<false,false,7,8><<<64*8, 256, 0, stream>>>(
      big, shdT, out, NTOK, DDIM, ISH, nullptr, nullptr, rslot, nullptr, ybuf);
}

// Round 17
// 377.643 us; speedup vs baseline: 1.0729x; 1.0049x over previous
//
#include <hip/hip_runtime.h>
#include <stdint.h>

#define NTOK 8192
#define DDIM 1024
#define NEXP 16
#define KSEL 2
#define ISH 2048
#define IEX 512
#define ALPHAC 1e-4f
#define REPS 1e-9f

typedef __attribute__((ext_vector_type(8))) short short8;
typedef __attribute__((ext_vector_type(4))) float f32x4;

__device__ __forceinline__ unsigned short f2bf(float f){
  union { float f; uint32_t u; } v; v.f = f;
  uint32_t u = v.u;
  uint32_t r = (u + 0x7fffu + ((u >> 16) & 1u)) >> 16;
  return (unsigned short)r;
}
__device__ __forceinline__ float bf2f(unsigned short h){
  union { uint32_t u; float f; } v; v.u = ((uint32_t)h) << 16; return v.f;
}

// async global->LDS, 16B per lane; LDS dest = wave-uniform base + lane*16
__device__ __forceinline__ void gload16(const void* g, void* l){
  __builtin_amdgcn_global_load_lds(
      (const __attribute__((address_space(1))) void*)g,
      (__attribute__((address_space(3))) void*)l, 16, 0, 0);
}

// ------- transpose + convert: in (R,C) f32 -> out row c of length R, bf16 (RM=1) -------
__global__ __launch_bounds__(256) void transpose_bf16(const float* __restrict__ in,
                                                      unsigned short* __restrict__ outp,
                                                      int R, int C){
  __shared__ float tile[64][65];
  const float* ip = in + (size_t)blockIdx.z * R * C;
  unsigned short* op = outp + (size_t)blockIdx.z * R * C;
  int c0 = blockIdx.x * 64, r0 = blockIdx.y * 64;
  int t = threadIdx.x;
  int tr = t >> 4, tc = (t & 15) * 4;
  #pragma unroll
  for (int i = 0; i < 4; ++i){
    float4 v = *(const float4*)&ip[(size_t)(r0 + tr + i*16) * C + c0 + tc];
    tile[tr + i*16][tc+0] = v.x;
    tile[tr + i*16][tc+1] = v.y;
    tile[tr + i*16][tc+2] = v.z;
    tile[tr + i*16][tc+3] = v.w;
  }
  __syncthreads();
  #pragma unroll
  for (int i = 0; i < 4; ++i){
    int oc = tr + i*16;
    ushort4 w;
    w.x = f2bf(tile[tc+0][oc]);
    w.y = f2bf(tile[tc+1][oc]);
    w.z = f2bf(tile[tc+2][oc]);
    w.w = f2bf(tile[tc+3][oc]);
    *(ushort4*)&op[(size_t)(c0 + oc) * R + r0 + tc] = w;
  }
}

// ------- z-selected interleaving transpose: z<nz -> in0 (even cols), z>=nz -> in1 (odd) -------
// Per-block work identical to the RM=2 single-source transpose (r16-measured); the z axis
// just carries both sources in one dispatch (no serialization, no extra barriers).
__global__ __launch_bounds__(256) void transpose2z(const float* __restrict__ in0,
                                                   const float* __restrict__ in1,
                                                   unsigned short* __restrict__ outp,
                                                   int R, int C, int nz){
  __shared__ float tile[64][65];
  const int z = blockIdx.z;
  const int ro = (z >= nz) ? 1 : 0;
  const int zz = ro ? z - nz : z;
  const float* ip = (ro ? in1 : in0) + (size_t)zz * R * C;
  unsigned short* op = outp + (size_t)zz * R * C * 2;
  int c0 = blockIdx.x * 64, r0 = blockIdx.y * 64;
  int t = threadIdx.x;
  int tr = t >> 4, tc = (t & 15) * 4;
  #pragma unroll
  for (int i = 0; i < 4; ++i){
    float4 v = *(const float4*)&ip[(size_t)(r0 + tr + i*16) * C + c0 + tc];
    tile[tr + i*16][tc+0] = v.x;
    tile[tr + i*16][tc+1] = v.y;
    tile[tr + i*16][tc+2] = v.z;
    tile[tr + i*16][tc+3] = v.w;
  }
  __syncthreads();
  #pragma unroll
  for (int i = 0; i < 4; ++i){
    int oc = tr + i*16;
    ushort4 w;
    w.x = f2bf(tile[tc+0][oc]);
    w.y = f2bf(tile[tc+1][oc]);
    w.z = f2bf(tile[tc+2][oc]);
    w.w = f2bf(tile[tc+3][oc]);
    *(ushort4*)&op[(size_t)((c0 + oc) * 2 + ro) * R + r0 + tc] = w;
  }
}

// ------- router stage 1: fp32 logits = x @ gw, wave-per-token; ALSO writes xb (bf16) -------
__global__ __launch_bounds__(256) void logits_kernel(
    const float* __restrict__ x, const float* __restrict__ gw,
    float* __restrict__ logits, unsigned short* __restrict__ xb)
{
  __shared__ float gws[16][1024];
  const int t = threadIdx.x;
  #pragma unroll
  for (int k = 0; k < 16; ++k){
    int idx = t + k * 256;
    float4 v = ((const float4*)gw)[idx];
    int d = idx >> 2, e0 = (idx & 3) * 4;
    gws[e0+0][d] = v.x;
    gws[e0+1][d] = v.y;
    gws[e0+2][d] = v.z;
    gws[e0+3][d] = v.w;
  }
  __syncthreads();
  const int lane = t & 63, w = t >> 6;
  const int nb = blockIdx.x * 16 + w * 4;
  for (int i = 0; i < 4; ++i){
    const int n = nb + i;
    const float4* xr = (const float4*)(x + (size_t)n * DDIM);
    ushort4* xo = (ushort4*)(xb + (size_t)n * DDIM);
    float4 xv[4];
    #pragma unroll
    for (int k = 0; k < 4; ++k) xv[k] = xr[lane + k*64];
    #pragma unroll
    for (int k = 0; k < 4; ++k){
      ushort4 ob;
      ob.x = f2bf(xv[k].x); ob.y = f2bf(xv[k].y);
      ob.z = f2bf(xv[k].z); ob.w = f2bf(xv[k].w);
      xo[lane + k*64] = ob;                 // fused f32->bf16 convert of x
    }
    float acc[16];
    #pragma unroll
    for (int e = 0; e < 16; ++e){
      float s = 0.f;
      #pragma unroll
      for (int k = 0; k < 4; ++k){
        float4 g = *(const float4*)&gws[e][(lane + k*64)*4];
        s = fmaf(xv[k].x, g.x, fmaf(xv[k].y, g.y, fmaf(xv[k].z, g.z, fmaf(xv[k].w, g.w, s))));
      }
      acc[e] = s;
    }
    #pragma unroll
    for (int m = 1; m < 64; m <<= 1)
      #pragma unroll
      for (int e = 0; e < 16; ++e)
        acc[e] += __shfl_xor(acc[e], m);
    if (lane == 0){
      float4* op = (float4*)(logits + (size_t)n * 16);
      op[0] = make_float4(acc[0],  acc[1],  acc[2],  acc[3]);
      op[1] = make_float4(acc[4],  acc[5],  acc[6],  acc[7]);
      op[2] = make_float4(acc[8],  acc[9],  acc[10], acc[11]);
      op[3] = make_float4(acc[12], acc[13], acc[14], acc[15]);
    }
  }
}

// ---------------- router stage 2: sigmoid, top-2, gates, P/C partials ----------------
__global__ __launch_bounds__(256) void router_finish(
    const float* __restrict__ logits, const float* __restrict__ ebias,
    int* __restrict__ idxb, float* __restrict__ gvb,
    float* __restrict__ Ppart, int* __restrict__ Cpart)
{
  __shared__ float Ps[16];
  __shared__ int Cs[16];
  const int t = threadIdx.x;
  if (t < 16){ Ps[t] = 0.f; Cs[t] = 0; }
  __syncthreads();
  const int lane = t & 63;
  const int n = blockIdx.x * 256 + t;
  const float4* lp = (const float4*)(logits + (size_t)n * 16);
  float4 a0 = lp[0], a1 = lp[1], a2 = lp[2], a3 = lp[3];
  float aff[16];
  aff[0]=a0.x; aff[1]=a0.y; aff[2]=a0.z; aff[3]=a0.w;
  aff[4]=a1.x; aff[5]=a1.y; aff[6]=a1.z; aff[7]=a1.w;
  aff[8]=a2.x; aff[9]=a2.y; aff[10]=a2.z; aff[11]=a2.w;
  aff[12]=a3.x; aff[13]=a3.y; aff[14]=a3.z; aff[15]=a3.w;
  float rowsum = REPS;
  #pragma unroll
  for (int e = 0; e < 16; ++e){
    aff[e] = 1.f / (1.f + __expf(-aff[e]));
    rowsum += aff[e];
  }
  float bj[16];
  #pragma unroll
  for (int e = 0; e < 16; ++e) bj[e] = ebias[e];
  float bestS = aff[0] + bj[0], bestA = aff[0]; int i1 = 0;
  #pragma unroll
  for (int j = 1; j < 16; ++j){
    float sc = aff[j] + bj[j];
    bool gt2 = sc > bestS;
    bestS = gt2 ? sc : bestS; bestA = gt2 ? aff[j] : bestA; i1 = gt2 ? j : i1;
  }
  float secS = -1e30f, secA = 0.f; int i2 = 0;
  #pragma unroll
  for (int j = 0; j < 16; ++j){
    float sc = aff[j] + bj[j];
    bool ok = (j != i1) && (sc > secS);
    secS = ok ? sc : secS; secA = ok ? aff[j] : secA; i2 = ok ? j : i2;
  }
  float den = bestA + secA + REPS;
  idxb[n*2]   = i1; idxb[n*2+1] = i2;
  gvb[n*2]    = bestA / den; gvb[n*2+1] = secA / den;

  float inv = 1.f / rowsum;
  float pv[16]; int cv[16];
  #pragma unroll
  for (int e = 0; e < 16; ++e){
    pv[e] = aff[e] * inv;
    cv[e] = (e == i1) + (e == i2);
  }
  #pragma unroll
  for (int m = 1; m < 64; m <<= 1)
    #pragma unroll
    for (int e = 0; e < 16; ++e){
      pv[e] += __shfl_xor(pv[e], m);
      cv[e] += __shfl_xor(cv[e], m);
    }
  if (lane == 0){
    #pragma unroll
    for (int e = 0; e < 16; ++e){
      atomicAdd(&Ps[e], pv[e]);
      atomicAdd(&Cs[e], cv[e]);
    }
  }
  __syncthreads();
  if (t < 16){ Ppart[blockIdx.x*16 + t] = Ps[t]; Cpart[blockIdx.x*16 + t] = Cs[t]; }
}

// ---------------- finalize: counts, offsets, cursors, balance loss, tail writes ----------------
__global__ __launch_bounds__(256) void finalize2(
    const float* __restrict__ Ppart, const int* __restrict__ Cpart,
    int* __restrict__ counts, int* __restrict__ offs, int* __restrict__ cursor,
    float* __restrict__ out_tail)
{
  __shared__ float P[16];
  __shared__ int C[16];
  int t = threadIdx.x;
  if (t < 16){ P[t] = 0.f; C[t] = 0; }
  __syncthreads();
  if (t < 32){
    int e = t & 15, c = t >> 4;
    float p = 0.f; int cc = 0;
    for (int b = c * 16; b < c * 16 + 16; ++b){ p += Ppart[b*16 + e]; cc += Cpart[b*16 + e]; }
    atomicAdd(&P[e], p); atomicAdd(&C[e], cc);
  }
  __syncthreads();
  if (t == 0){
    int a = 0; float loss = 0.f;
    for (int i = 0; i < 16; ++i){
      offs[i] = a; cursor[i] = a; counts[i] = C[i]; a += C[i];
      loss += ((float)C[i] * (float)NEXP / (float)(KSEL * NTOK)) * (P[i] / (float)NTOK);
      out_tail[1+i] = (float)C[i];
    }
    out_tail[0] = ALPHAC * loss;
  }
}

// ---------------- slot assignment into per-expert contiguous groups ----------------
__global__ __launch_bounds__(256) void slot_assign(
    const int* __restrict__ idxb, const float* __restrict__ gvb,
    int* __restrict__ cursor, int* __restrict__ tokp, float* __restrict__ gatep,
    int* __restrict__ rslot)
{
  int i = blockIdx.x * 256 + threadIdx.x;   // (n,k) flat, 0..16383
  int e = idxb[i];
  int s = atomicAdd(&cursor[e], 1);
  tokp[s] = i >> 1;
  gatep[s] = gvb[i];
  rslot[i] = s;
}

// ---------------- 128x128xBK64 bf16 MFMA GEMM, single-buffered (m97 structure) ----------
// MODE: 1 = f32 store; 2 = bf16 * rowscale;
//       6 = interleaved gate/up -> silu(even col)*odd col, store N/2 cols bf16;
//       7 = f32 store of val + yb[perm[2*row]][col] + yb[perm[2*row+1]][col] (fused combine).
template<bool GROUPED, bool GATHER, int MODE, int NYT>
__global__ __launch_bounds__(256) void gemm128(
    const unsigned short* __restrict__ A,
    const unsigned short* __restrict__ B,
    void* __restrict__ Cout,
    int M, int N, int K,
    const int* __restrict__ counts,
    const int* __restrict__ offsets,
    const int* __restrict__ perm,
    const float* __restrict__ rowscale,
    const unsigned short* __restrict__ yb)
{
  __shared__ __align__(16) unsigned short As[128*64];
  __shared__ __align__(16) unsigned short Bs[128*64];

  const int nwg = gridDim.x;
  const int bid = blockIdx.x;
  const int wg = (bid & 7) * (nwg >> 3) + (bid >> 3);   // XCD-contiguous chunks
  const int mtl = wg / NYT;
  const int nt  = wg % NYT;

  int mt = mtl, off = 0, cnt = M;
  const unsigned short* bp = B;
  if (GROUPED){
    int acc_ = 0, e = -1;
    #pragma unroll
    for (int i = 0; i < NEXP; ++i){
      int c = counts[i]; int tt = (c + 127) >> 7;
      if (e < 0 && mtl < acc_ + tt){ e = i; mt = mtl - acc_; off = offsets[i]; cnt = c; }
      acc_ += tt;
    }
    if (e < 0) return;
    bp += (size_t)e * N * K;
  }
  const int m0 = mt * 128, n0 = nt * 128;
  const int t = threadIdx.x;
  const int lane = t & 63;
  const int wid = t >> 6;
  const int wm = (wid >> 1) * 64;
  const int wn = (wid & 1) * 64;
  const int l15 = lane & 15, g = lane >> 4;

  const unsigned short* asrc[4];
  const unsigned short* bsrc[4];
  int ldso[4];
  #pragma unroll
  for (int c = 0; c < 4; ++c){
    int s = (wid*4 + c)*64 + lane;
    int row = s >> 3, c16 = s & 7;
    int scol = (c16 ^ (row & 7)) * 8;
    ldso[c] = (wid*4 + c) * 512;
    int r = m0 + row;
    int rc = GROUPED ? (r < cnt ? r : (cnt > 0 ? cnt - 1 : 0)) : r;
    int ar;
    if (GATHER) ar = perm[off + rc];
    else        ar = GROUPED ? off + rc : rc;
    asrc[c] = A + (size_t)ar * K + scol;
    bsrc[c] = bp + (size_t)(n0 + row) * K + scol;
  }

  f32x4 acc[4][4];
  #pragma unroll
  for (int i = 0; i < 4; ++i)
    #pragma unroll
    for (int j = 0; j < 4; ++j)
      #pragma unroll
      for (int r = 0; r < 4; ++r) acc[i][j][r] = 0.f;

  const int ntk = K >> 6;
  for (int tk = 0; tk < ntk; ++tk){
    const int k0 = tk << 6;
    #pragma unroll
    for (int c = 0; c < 4; ++c) gload16(asrc[c] + k0, (void*)&As[ldso[c]]);
    #pragma unroll
    for (int c = 0; c < 4; ++c) gload16(bsrc[c] + k0, (void*)&Bs[ldso[c]]);
    __syncthreads();
    #pragma unroll
    for (int ks = 0; ks < 2; ++ks){
      short8 af[4], bf[4];
      #pragma unroll
      for (int i = 0; i < 4; ++i){
        int row = wm + i * 16 + l15;
        af[i] = *(const short8*)&As[row * 64 + (((ks*4 + g) ^ (row & 7)) * 8)];
      }
      #pragma unroll
      for (int j = 0; j < 4; ++j){
        int row = wn + j * 16 + l15;
        bf[j] = *(const short8*)&Bs[row * 64 + (((ks*4 + g) ^ (row & 7)) * 8)];
      }
      #pragma unroll
      for (int i = 0; i < 4; ++i)
        #pragma unroll
        for (int j = 0; j < 4; ++j)
          acc[i][j] = __builtin_amdgcn_mfma_f32_16x16x32_bf16(af[i], bf[j], acc[i][j], 0, 0, 0);
    }
    __syncthreads();
  }

  // epilogue: D[row=(l>>4)*4+r][col=l&15] per 16x16 fragment (m89-verified layout)
  #pragma unroll
  for (int i = 0; i < 4; ++i)
    #pragma unroll
    for (int j = 0; j < 4; ++j)
      #pragma unroll
      for (int r = 0; r < 4; ++r){
        int lr = wm + i * 16 + g * 4 + r;
        int grow = m0 + lr;
        if (GROUPED && grow >= cnt) continue;
        int gcol = n0 + wn + j * 16 + l15;
        size_t orow = GROUPED ? (size_t)(off + grow) : (size_t)grow;
        float val = acc[i][j][r];
        if (MODE == 1){
          ((float*)Cout)[orow * N + gcol] = val;
        } else if (MODE == 2){
          val *= rowscale[off + grow];
          ((unsigned short*)Cout)[orow * N + gcol] = f2bf(val);
        } else if (MODE == 6){
          float uo = __shfl_xor(val, 1);        // partner column (same row)
          if (!(l15 & 1)){
            float rv = val / (1.f + __expf(-val)) * uo;   // silu(gate)*up
            ((unsigned short*)Cout)[orow * (N >> 1) + (gcol >> 1)] = f2bf(rv);
          }
        } else if (MODE == 7){
          int s0 = perm[grow*2], s1 = perm[grow*2+1];
          float add = bf2f(yb[(size_t)s0 * N + gcol]) + bf2f(yb[(size_t)s1 * N + gcol]);
          ((float*)Cout)[orow * N + gcol] = val + add;
        }
      }
}

// ---------------- 256x256xBK64 bf16 MFMA GEMM, T3-minimum 2-phase (m230-V0) ----------
// MODE 6 only: interleaved gate/up -> silu(even)*odd, store N/2 cols bf16.
template<int MODE, int NYT>
__global__ __launch_bounds__(512, 1) void gemm256(
    const unsigned short* __restrict__ A,
    const unsigned short* __restrict__ B,
    void* __restrict__ Cout,
    int M, int N, int K)
{
  __shared__ __align__(16) unsigned short As[2][256*64];
  __shared__ __align__(16) unsigned short Bs[2][256*64];

  const int nwg = gridDim.x;
  const int bid = blockIdx.x;
  const int wg = (bid & 7) * (nwg >> 3) + (bid >> 3);
  const int mt  = wg / NYT;
  const int ntc = wg % NYT;

  const int m0 = mt * 256, n0 = ntc * 256;
  const int t = threadIdx.x;
  const int lane = t & 63;
  const int wid = t >> 6;
  const int wm0 = (wid >> 2) * 128;
  const int wn0 = (wid & 3) * 64;
  const int l15 = lane & 15, g = lane >> 4;

  const unsigned short* asrc[4];
  const unsigned short* bsrc[4];
  int ldst[4];
  #pragma unroll
  for (int c = 0; c < 4; ++c){
    int slot = c * 512 + t;
    int row = slot >> 3, c16 = slot & 7;
    int scol = (c16 ^ (row & 7)) * 8;
    ldst[c] = slot * 8;
    asrc[c] = A + (size_t)(m0 + row) * K + scol;
    bsrc[c] = B + (size_t)(n0 + row) * K + scol;
  }

  f32x4 acc[8][4];
  #pragma unroll
  for (int i = 0; i < 8; ++i)
    #pragma unroll
    for (int j = 0; j < 4; ++j)
      #pragma unroll
      for (int r = 0; r < 4; ++r) acc[i][j][r] = 0.f;

  auto STAGE = [&](int buf, int kt){
    const int k0 = kt << 6;
    #pragma unroll
    for (int c = 0; c < 4; ++c) gload16(asrc[c] + k0, (void*)&As[buf][ldst[c]]);
    #pragma unroll
    for (int c = 0; c < 4; ++c) gload16(bsrc[c] + k0, (void*)&Bs[buf][ldst[c]]);
  };

  const int ntk = K >> 6;
  STAGE(0, 0);
  __syncthreads();
  int cur = 0;
  for (int tk = 0; tk < ntk; ++tk){
    if (tk + 1 < ntk) STAGE(cur ^ 1, tk + 1);   // issue next tile FIRST (async)
    short8 bfr[4][2];
    #pragma unroll
    for (int j = 0; j < 4; ++j)
      #pragma unroll
      for (int ks = 0; ks < 2; ++ks){
        int row = wn0 + j * 16 + l15;
        bfr[j][ks] = *(const short8*)&Bs[cur][row * 64 + (((ks*4 + g) ^ (row & 7)) * 8)];
      }
    #pragma unroll
    for (int mi = 0; mi < 8; ++mi){
      int row = wm0 + mi * 16 + l15;
      short8 af0 = *(const short8*)&As[cur][row * 64 + (((0 + g) ^ (row & 7)) * 8)];
      short8 af1 = *(const short8*)&As[cur][row * 64 + (((4 + g) ^ (row & 7)) * 8)];
      #pragma unroll
      for (int j = 0; j < 4; ++j)
        acc[mi][j] = __builtin_amdgcn_mfma_f32_16x16x32_bf16(af0, bfr[j][0], acc[mi][j], 0, 0, 0);
      #pragma unroll
      for (int j = 0; j < 4; ++j)
        acc[mi][j] = __builtin_amdgcn_mfma_f32_16x16x32_bf16(af1, bfr[j][1], acc[mi][j], 0, 0, 0);
    }
    __syncthreads();
    cur ^= 1;
  }

  #pragma unroll
  for (int mi = 0; mi < 8; ++mi)
    #pragma unroll
    for (int j = 0; j < 4; ++j)
      #pragma unroll
      for (int r = 0; r < 4; ++r){
        int lr = wm0 + mi * 16 + g * 4 + r;
        int grow = m0 + lr;
        int gcol = n0 + wn0 + j * 16 + l15;
        float val = acc[mi][j][r];
        if (MODE == 6){
          float uo = __shfl_xor(val, 1);
          if (!(l15 & 1)){
            float rv = val / (1.f + __expf(-val)) * uo;   // silu(gate)*up
            ((unsigned short*)Cout)[(size_t)grow * (N >> 1) + (gcol >> 1)] = f2bf(rv);
          }
        } else {
          ((float*)Cout)[(size_t)grow * N + gcol] = val;
        }
      }
}

extern "C" void kernel_launch(void* const* d_in, const int* in_sizes, int n_in,
                              void* d_out, int out_size, void* d_ws, size_t ws_size,
                              hipStream_t stream)
{
  const float* x       = (const float*)d_in[0];
  const float* gate_w  = (const float*)d_in[1];
  const float* ebias   = (const float*)d_in[2];
  const float* sh_gate = (const float*)d_in[3];
  const float* sh_up   = (const float*)d_in[4];
  const float* sh_down = (const float*)d_in[5];
  const float* ex_gate = (const float*)d_in[6];
  const float* ex_up   = (const float*)d_in[7];
  const float* ex_down = (const float*)d_in[8];
  float* out = (float*)d_out;
  (void)in_sizes; (void)n_in; (void)out_size; (void)ws_size;

  size_t o = 0;
  auto alloc = [&](size_t bytes) -> void* {
    o = (o + 255) & ~(size_t)255;
    void* p = (char*)d_ws + o;
    o += bytes;
    return p;
  };
  unsigned short* xb    = (unsigned short*)alloc((size_t)NTOK*DDIM*2);
  unsigned short* shguT = (unsigned short*)alloc((size_t)2*ISH*DDIM*2);       // interleaved g/u
  unsigned short* shdT  = (unsigned short*)alloc((size_t)DDIM*ISH*2);
  unsigned short* exguT = (unsigned short*)alloc((size_t)NEXP*2*IEX*DDIM*2);  // interleaved g/u
  unsigned short* exdT  = (unsigned short*)alloc((size_t)NEXP*DDIM*IEX*2);
  unsigned short* hbuf  = (unsigned short*)alloc((size_t)NTOK*KSEL*IEX*2);
  unsigned short* big   = (unsigned short*)alloc((size_t)NTOK*ISH*2);        // shared smid
  unsigned short* ybuf  = (unsigned short*)alloc((size_t)NTOK*KSEL*DDIM*2);  // routed outputs
  float* logits = (float*)alloc((size_t)NTOK*NEXP*4);
  int*   idxb  = (int*)alloc(NTOK*KSEL*4);
  float* gvb   = (float*)alloc(NTOK*KSEL*4);
  float* Ppart = (float*)alloc(32*16*4);
  int*   Cpart = (int*)alloc(32*16*4);
  int*   counts= (int*)alloc(64);
  int*   offs  = (int*)alloc(64);
  int*   cursor= (int*)alloc(64);
  int*   tokp  = (int*)alloc(NTOK*KSEL*4);
  float* gatep = (float*)alloc(NTOK*KSEL*4);
  int*   rslot = (int*)alloc(NTOK*KSEL*4);

  // weight prep (x convert fused into logits_kernel; gate/up pairs share one z-extended launch)
  transpose2z<<<dim3(ISH/64, DDIM/64, 2),       256, 0, stream>>>(sh_gate, sh_up, shguT, DDIM, ISH, 1);
  transpose_bf16<<<dim3(DDIM/64, ISH/64, 1),    256, 0, stream>>>(sh_down, shdT, ISH, DDIM);
  transpose2z<<<dim3(IEX/64, DDIM/64, 2*NEXP),  256, 0, stream>>>(ex_gate, ex_up, exguT, DDIM, IEX, NEXP);
  transpose_bf16<<<dim3(DDIM/64, IEX/64, NEXP), 256, 0, stream>>>(ex_down, exdT, IEX, DDIM);

  // routing (+ fused x->bf16 convert)
  logits_kernel<<<512, 256, 0, stream>>>(x, gate_w, logits, xb);
  router_finish<<<32, 256, 0, stream>>>(logits, ebias, idxb, gvb, Ppart, Cpart);
  finalize2<<<1, 256, 0, stream>>>(Ppart, Cpart, counts, offs, cursor,
                                   out + (size_t)NTOK*DDIM);
  slot_assign<<<NTOK*KSEL/256, 256, 0, stream>>>(idxb, gvb, cursor, tokp, gatep, rslot);

  // routed experts first (stream order guarantees ybuf ready for the fused combine):
  // hbuf = silu(x@gate)*(x@up); ybuf = gate * (hbuf@down)
  gemm128<true,true,6,8><<<144*8, 256, 0, stream>>>(
      xb, exguT, hbuf, 0, 2*IEX, DDIM, counts, offs, tokp, nullptr, nullptr);
  gemm128<true,false,2,8><<<144*8, 256, 0, stream>>>(
      hbuf, exdT, ybuf, 0, DDIM, IEX, counts, offs, nullptr, gatep, nullptr);

  // shared expert: big = silu(x@sh_gate)*(x@sh_up) fused (256², grid 512);
  // out = big@sh_down + ybuf[slot0] + ybuf[slot1]  (combine fused into epilogue)
  gemm256<6,16><<<32*16, 512, 0, stream>>>(
      xb, shguT, big, NTOK, 2*ISH, DDIM);
  gemm128<false,false,7,8><<<64*8, 256, 0, stream>>>(
      big, shdT, out, NTOK, DDIM, ISH, nullptr, nullptr, rslot, nullptr, ybuf);
}